// Round 2
// baseline (14097.229 us; speedup 1.0000x reference)
//
#include <hip/hip_runtime.h>
#include <hip/hip_bf16.h>

#define N_NODES 50000
#define N_EDGES 800000
#define F_IN 9
#define H 128
#define G_GRAPHS 64

// ---------- helpers ----------
__device__ inline unsigned encodef(float f) {
    unsigned u = __float_as_uint(f);
    return (u & 0x80000000u) ? ~u : (u | 0x80000000u);
}
__device__ inline float decodef(unsigned u) {
    return __uint_as_float((u & 0x80000000u) ? (u ^ 0x80000000u) : ~u);
}

// ---------- dtype detection ----------
// Reads 256 uint32 words of x. If x is packed bf16, the LOW half of each word
// is a bf16 of ~N(0,1): exponent bits (word>>7)&0xFF land in [0x70,0x83] with
// prob ~99%. If x is f32, those bits are middle mantissa bits (~uniform, ~8%).
__global__ __launch_bounds__(256) void k_detect(const unsigned* __restrict__ x, int* flag) {
    __shared__ int cnt;
    if (threadIdx.x == 0) cnt = 0;
    __syncthreads();
    unsigned u = x[threadIdx.x];
    int e = (u >> 7) & 0xFF;
    if (e >= 0x70 && e <= 0x83) atomicAdd(&cnt, 1);
    __syncthreads();
    if (threadIdx.x == 0) *flag = (cnt >= 128) ? 1 : 0;
}

// ---------- convert input (f32 or bf16) to f32 workspace ----------
__global__ __launch_bounds__(256) void k_cvt(const void* __restrict__ src, float* __restrict__ dst,
                                             int n, const int* __restrict__ flag) {
    int i = blockIdx.x * 256 + threadIdx.x;
    if (i >= n) return;
    if (*flag)
        dst[i] = __bfloat162float(((const __hip_bfloat16*)src)[i]);
    else
        dst[i] = ((const float*)src)[i];
}

__global__ __launch_bounds__(256) void k_zero(float* p, int n) {
    int i = blockIdx.x * 256 + threadIdx.x;
    if (i < n) p[i] = 0.f;
}

// ---------- degree / normalization ----------
__global__ __launch_bounds__(256) void k_deg(const int* __restrict__ dst, float* deg) {
    int e = blockIdx.x * 256 + threadIdx.x;
    if (e < N_EDGES) atomicAdd(&deg[dst[e]], 1.0f);
}

__global__ __launch_bounds__(256) void k_dis(float* deg_dis) {
    int n = blockIdx.x * 256 + threadIdx.x;
    if (n < N_NODES) deg_dis[n] = rsqrtf(deg_dis[n] + 1.0f);
}

// ---------- generic GEMM: out[M,Nc] = act(A[M,K] @ Weff[K,Nc] + bias) ----------
// wsub: Weff[k][c] = W[k][c] - W[K+k][c]
// act: 0 none, 1 tanh
__global__ __launch_bounds__(256) void k_gemm(const float* __restrict__ A,
                                              const float* __restrict__ W,
                                              const float* __restrict__ bias,
                                              float* __restrict__ out,
                                              int M, int K, int Nc, int wsub, int act) {
    int idx = blockIdx.x * 256 + threadIdx.x;
    int perRow = Nc >> 2;
    int row = idx / perRow;
    int c4 = (idx - row * perRow) << 2;
    if (row >= M) return;
    float acc0 = 0.f, acc1 = 0.f, acc2 = 0.f, acc3 = 0.f;
    const float* a = A + (size_t)row * K;
    if (wsub) {
        #pragma unroll 4
        for (int k = 0; k < K; ++k) {
            float av = a[k];
            float4 w  = *reinterpret_cast<const float4*>(&W[(size_t)k * Nc + c4]);
            float4 w2 = *reinterpret_cast<const float4*>(&W[(size_t)(K + k) * Nc + c4]);
            acc0 = fmaf(av, w.x - w2.x, acc0);
            acc1 = fmaf(av, w.y - w2.y, acc1);
            acc2 = fmaf(av, w.z - w2.z, acc2);
            acc3 = fmaf(av, w.w - w2.w, acc3);
        }
    } else {
        #pragma unroll 4
        for (int k = 0; k < K; ++k) {
            float av = a[k];
            float4 w = *reinterpret_cast<const float4*>(&W[(size_t)k * Nc + c4]);
            acc0 = fmaf(av, w.x, acc0);
            acc1 = fmaf(av, w.y, acc1);
            acc2 = fmaf(av, w.z, acc2);
            acc3 = fmaf(av, w.w, acc3);
        }
    }
    if (bias) {
        acc0 += bias[c4 + 0]; acc1 += bias[c4 + 1];
        acc2 += bias[c4 + 2]; acc3 += bias[c4 + 3];
    }
    if (act) {
        acc0 = tanhf(acc0); acc1 = tanhf(acc1);
        acc2 = tanhf(acc2); acc3 = tanhf(acc3);
    }
    float4 r = make_float4(acc0, acc1, acc2, acc3);
    *reinterpret_cast<float4*>(&out[(size_t)row * Nc + c4]) = r;
}

// ---------- GCN scatter-add: agg[dst] += h[src] * dis[src] ----------
__global__ __launch_bounds__(256) void k_gcn_agg(const int* __restrict__ src,
                                                 const int* __restrict__ dst,
                                                 const float* __restrict__ h,
                                                 const float* __restrict__ dis,
                                                 float* agg) {
    int idx = blockIdx.x * 256 + threadIdx.x;   // 32 threads/edge, 4 cols each
    int e = idx >> 5;
    int c4 = (idx & 31) << 2;
    if (e >= N_EDGES) return;
    int s = src[e], d = dst[e];
    float ds = dis[s];
    float4 hv = *reinterpret_cast<const float4*>(&h[(size_t)s * H + c4]);
    float* ap = &agg[(size_t)d * H + c4];
    atomicAdd(ap + 0, hv.x * ds);
    atomicAdd(ap + 1, hv.y * ds);
    atomicAdd(ap + 2, hv.z * ds);
    atomicAdd(ap + 3, hv.w * ds);
}

// ---------- GCN combine: out = tanh(dis*agg + hW*dis^2 + b) ----------
__global__ __launch_bounds__(256) void k_gcn_combine(const float* __restrict__ hW,
                                                     const float* __restrict__ agg,
                                                     const float* __restrict__ dis,
                                                     const float* __restrict__ bias,
                                                     float* __restrict__ out) {
    int idx = blockIdx.x * 256 + threadIdx.x;
    int n = idx >> 5;
    int c4 = (idx & 31) << 2;
    if (n >= N_NODES) return;
    float dn = dis[n];
    float dn2 = dn * dn;
    float4 a  = *reinterpret_cast<const float4*>(&agg[(size_t)n * H + c4]);
    float4 hw = *reinterpret_cast<const float4*>(&hW[(size_t)n * H + c4]);
    float4 r;
    r.x = tanhf(dn * a.x + hw.x * dn2 + bias[c4 + 0]);
    r.y = tanhf(dn * a.y + hw.y * dn2 + bias[c4 + 1]);
    r.z = tanhf(dn * a.z + hw.z * dn2 + bias[c4 + 2]);
    r.w = tanhf(dn * a.w + hw.w * dn2 + bias[c4 + 3]);
    *reinterpret_cast<float4*>(&out[(size_t)n * H + c4]) = r;
}

// ---------- EdgeConv per-edge MLP + segment-max ----------
// t = relu(U[dst] + V[src]); w = t @ We2; atomicMax(aggEnc[dst], encode(w))
__global__ __launch_bounds__(256) void k_edgeconv_edges(const int* __restrict__ src,
                                                        const int* __restrict__ dst,
                                                        const float* __restrict__ U,
                                                        const float* __restrict__ V,
                                                        const float* __restrict__ We2,
                                                        unsigned* aggEnc) {
    __shared__ float t_lds[4][H];
    int lane = threadIdx.x & 63;
    int wv = threadIdx.x >> 6;
    int e = blockIdx.x * 4 + wv;        // grid sized exactly: E % 4 == 0
    int s = src[e], d = dst[e];
    int c0 = lane * 2;
    float2 uv = *reinterpret_cast<const float2*>(&U[(size_t)d * H + c0]);
    float2 vv = *reinterpret_cast<const float2*>(&V[(size_t)s * H + c0]);
    t_lds[wv][c0 + 0] = fmaxf(uv.x + vv.x, 0.f);
    t_lds[wv][c0 + 1] = fmaxf(uv.y + vv.y, 0.f);
    __syncthreads();
    float acc0 = 0.f, acc1 = 0.f;
    #pragma unroll 8
    for (int k = 0; k < H; ++k) {
        float tk = t_lds[wv][k];
        float2 w = *reinterpret_cast<const float2*>(&We2[(size_t)k * H + c0]);
        acc0 = fmaf(tk, w.x, acc0);
        acc1 = fmaf(tk, w.y, acc1);
    }
    unsigned* ap = aggEnc + (size_t)d * H + c0;
    atomicMax(ap + 0, encodef(acc0));
    atomicMax(ap + 1, encodef(acc1));
}

// ---------- EdgeConv combine: out = tanh(empty ? 0 : decode(max) + be2) ----------
__global__ __launch_bounds__(256) void k_edgeconv_combine(const unsigned* aggEnc,
                                                          const float* __restrict__ be2,
                                                          float* out) {
    int idx = blockIdx.x * 256 + threadIdx.x;
    int n = idx >> 5;
    int c4 = (idx & 31) << 2;
    if (n >= N_NODES) return;
    #pragma unroll
    for (int j = 0; j < 4; ++j) {
        unsigned u = aggEnc[(size_t)n * H + c4 + j];
        float v = (u == 0u) ? 0.f : (decodef(u) + be2[c4 + j]);
        out[(size_t)n * H + c4 + j] = tanhf(v);
    }
}

// ---------- final per-node scalar + batch-mean pooling ----------
__global__ __launch_bounds__(256) void k_pool(const float* __restrict__ f2,
                                              const float* __restrict__ Wf3,
                                              const float* __restrict__ bf3,
                                              const int* __restrict__ batch,
                                              float* pooled, float* counts) {
    __shared__ float lp[G_GRAPHS];
    __shared__ float lc[G_GRAPHS];
    int tid = threadIdx.x;
    if (tid < G_GRAPHS) { lp[tid] = 0.f; lc[tid] = 0.f; }
    __syncthreads();
    int n = blockIdx.x * 256 + tid;
    if (n < N_NODES) {
        float s = bf3[0];
        #pragma unroll
        for (int k = 0; k < 32; ++k) s = fmaf(f2[(size_t)n * 32 + k], Wf3[k], s);
        int b = batch[n];
        atomicAdd(&lp[b], s);
        atomicAdd(&lc[b], 1.0f);
    }
    __syncthreads();
    if (tid < G_GRAPHS && lc[tid] > 0.f) {
        atomicAdd(&pooled[tid], lp[tid]);
        atomicAdd(&counts[tid], lc[tid]);
    }
}

// Output dtype adaptive: bf16 if flag, else f32.
__global__ __launch_bounds__(64) void k_final(const float* pooled, const float* counts,
                                              void* out, const int* __restrict__ flag) {
    int g = threadIdx.x;
    if (g < G_GRAPHS) {
        float v = pooled[g] / fmaxf(counts[g], 1.0f);
        float s = 1.0f / (1.0f + expf(-v));
        if (*flag) ((__hip_bfloat16*)out)[g] = __float2bfloat16(s);
        else       ((float*)out)[g] = s;
    }
}

extern "C" void kernel_launch(void* const* d_in, const int* in_sizes, int n_in,
                              void* d_out, int out_size, void* d_ws, size_t ws_size,
                              hipStream_t stream) {
    const int* ei    = (const int*)d_in[1];
    const int* src   = ei;
    const int* dst   = ei + N_EDGES;
    const int* batch = (const int*)d_in[2];

    float* ws = (float*)d_ws;
    size_t off = 0;
    auto alloc = [&](size_t n) { float* p = ws + off; off += n; return p; };

    const size_t NH = (size_t)N_NODES * H;
    float* bufA   = alloc(NH);   // h / aggEnc(max) -> updated h
    float* bufB   = alloc(NH);   // h@W tmp / U / f1
    float* bufC   = alloc(NH);   // gcn agg / V / f2
    float* dis    = alloc(N_NODES);
    float* pooled = alloc(G_GRAPHS);
    float* counts = alloc(G_GRAPHS);
    int*   flag   = (int*)alloc(4);

    // converted-to-f32 inputs
    float* xf  = alloc((size_t)N_NODES * F_IN);
    float* W1  = alloc(F_IN * H);
    float* b1  = alloc(H);
    float* W2  = alloc(H * H);
    float* b2  = alloc(H);
    float* We1 = alloc(2 * H * H);
    float* be1 = alloc(H);
    float* We2 = alloc(H * H);
    float* be2 = alloc(H);
    float* Wf1 = alloc(H * H);
    float* bf1 = alloc(H);
    float* Wf2 = alloc(H * 32);
    float* bf2 = alloc(32);
    float* Wf3 = alloc(32);
    float* bf3 = alloc(4);

    const int nBlocksE1 = (N_EDGES + 255) / 256;
    const int nBlocksN1 = (N_NODES + 255) / 256;
    const int gemmBlocks  = (int)(((size_t)N_NODES * (H / 4) + 255) / 256);
    const int gemm2Blocks = (int)(((size_t)N_NODES * (32 / 4) + 255) / 256);
    const int eBlocks = (int)(((size_t)N_EDGES * 32 + 255) / 256);
    const int nBlocks = (int)(((size_t)N_NODES * 32 + 255) / 256);
    const int zBlocks = (int)((NH + 255) / 256);

    // dtype detection + input conversion
    k_detect<<<1, 256, 0, stream>>>((const unsigned*)d_in[0], flag);
    auto cvt = [&](int idx, float* dstp, int n) {
        k_cvt<<<(n + 255) / 256, 256, 0, stream>>>(d_in[idx], dstp, n, flag);
    };
    cvt(0,  xf,  N_NODES * F_IN);
    cvt(3,  W1,  F_IN * H);
    cvt(4,  b1,  H);
    cvt(5,  W2,  H * H);
    cvt(6,  b2,  H);
    cvt(7,  We1, 2 * H * H);
    cvt(8,  be1, H);
    cvt(9,  We2, H * H);
    cvt(10, be2, H);
    cvt(11, Wf1, H * H);
    cvt(12, bf1, H);
    cvt(13, Wf2, H * 32);
    cvt(14, bf2, 32);
    cvt(15, Wf3, 32);
    cvt(16, bf3, 1);

    // degree + normalization
    k_zero<<<(N_NODES + 255) / 256, 256, 0, stream>>>(dis, N_NODES);
    k_zero<<<1, 256, 0, stream>>>(pooled, 2 * G_GRAPHS);
    k_deg<<<nBlocksE1, 256, 0, stream>>>(dst, dis);
    k_dis<<<nBlocksN1, 256, 0, stream>>>(dis);

    // GCN1: tmp = x @ W1 -> bufB ; agg -> bufC ; combine -> bufA
    k_gemm<<<gemmBlocks, 256, 0, stream>>>(xf, W1, nullptr, bufB, N_NODES, F_IN, H, 0, 0);
    k_zero<<<zBlocks, 256, 0, stream>>>(bufC, (int)NH);
    k_gcn_agg<<<eBlocks, 256, 0, stream>>>(src, dst, bufB, dis, bufC);
    k_gcn_combine<<<nBlocks, 256, 0, stream>>>(bufB, bufC, dis, b1, bufA);

    for (int iter = 0; iter < 3; ++iter) {
        // EdgeConv on bufA: U = A@(We1a - We1b) + be1 -> bufB ; V = A@We1b -> bufC
        k_gemm<<<gemmBlocks, 256, 0, stream>>>(bufA, We1, be1, bufB, N_NODES, H, H, 1, 0);
        k_gemm<<<gemmBlocks, 256, 0, stream>>>(bufA, We1 + (size_t)H * H, nullptr, bufC, N_NODES, H, H, 0, 0);
        k_zero<<<zBlocks, 256, 0, stream>>>(bufA, (int)NH);   // encoded 0 == empty
        k_edgeconv_edges<<<N_EDGES / 4, 256, 0, stream>>>(src, dst, bufB, bufC, We2, (unsigned*)bufA);
        k_edgeconv_combine<<<nBlocks, 256, 0, stream>>>((unsigned*)bufA, be2, bufA);
        if (iter < 2) {
            k_gemm<<<gemmBlocks, 256, 0, stream>>>(bufA, W2, nullptr, bufB, N_NODES, H, H, 0, 0);
            k_zero<<<zBlocks, 256, 0, stream>>>(bufC, (int)NH);
            k_gcn_agg<<<eBlocks, 256, 0, stream>>>(src, dst, bufB, dis, bufC);
            k_gcn_combine<<<nBlocks, 256, 0, stream>>>(bufB, bufC, dis, b2, bufA);
        }
    }

    // final MLP
    k_gemm<<<gemmBlocks, 256, 0, stream>>>(bufA, Wf1, bf1, bufB, N_NODES, H, H, 0, 1);
    k_gemm<<<gemm2Blocks, 256, 0, stream>>>(bufB, Wf2, bf2, bufC, N_NODES, H, 32, 0, 1);
    k_pool<<<nBlocksN1, 256, 0, stream>>>(bufC, Wf3, bf3, batch, pooled, counts);
    k_final<<<1, 64, 0, stream>>>(pooled, counts, d_out, flag);
}

// Round 3
// 5221.857 us; speedup vs baseline: 2.6997x; 2.6997x over previous
//
#include <hip/hip_runtime.h>
#include <hip/hip_bf16.h>

#define N_NODES 50000
#define N_EDGES 800000
#define F_IN 9
#define H 128
#define G_GRAPHS 64
#define HH (H * H)

// ---------- dtype detection ----------
__global__ __launch_bounds__(256) void k_detect(const unsigned* __restrict__ x, int* flag) {
    __shared__ int cnt;
    if (threadIdx.x == 0) cnt = 0;
    __syncthreads();
    unsigned u = x[threadIdx.x];
    int e = (u >> 7) & 0xFF;
    if (e >= 0x70 && e <= 0x83) atomicAdd(&cnt, 1);
    __syncthreads();
    if (threadIdx.x == 0) *flag = (cnt >= 128) ? 1 : 0;
}

// ---------- convert input (f32 or bf16) to f32 workspace ----------
__global__ __launch_bounds__(256) void k_cvt(const void* __restrict__ src, float* __restrict__ dst,
                                             int n, const int* __restrict__ flag) {
    int i = blockIdx.x * 256 + threadIdx.x;
    if (i >= n) return;
    if (*flag)
        dst[i] = __bfloat162float(((const __hip_bfloat16*)src)[i]);
    else
        dst[i] = ((const float*)src)[i];
}

__global__ __launch_bounds__(256) void k_zero(float* p, int n) {
    int i = blockIdx.x * 256 + threadIdx.x;
    if (i < n) p[i] = 0.f;
}

// in-place: We1f[i] -= We1f[HH+i]  (Weff = We1a - We1b)
__global__ __launch_bounds__(256) void k_sub(float* w) {
    int i = blockIdx.x * 256 + threadIdx.x;
    if (i < HH) w[i] -= w[HH + i];
}

// ---------- CSR build ----------
__global__ __launch_bounds__(256) void k_hist(const int* __restrict__ dst, int* cnt) {
    int e = blockIdx.x * 256 + threadIdx.x;
    if (e < N_EDGES) atomicAdd(&cnt[dst[e]], 1);
}

// exclusive scan, 2048 elements per block
__global__ __launch_bounds__(256) void k_scan1(const int* __restrict__ deg, int* __restrict__ out,
                                               int* __restrict__ blockSums) {
    __shared__ int lds[256];
    int base = blockIdx.x * 2048;
    int t = threadIdx.x;
    int local[8];
    int s = 0;
    #pragma unroll
    for (int j = 0; j < 8; ++j) {
        int idx = base + t * 8 + j;
        int v = (idx < N_NODES) ? deg[idx] : 0;
        local[j] = s;
        s += v;
    }
    lds[t] = s;
    __syncthreads();
    if (t == 0) {
        int run = 0;
        for (int i = 0; i < 256; ++i) { int v = lds[i]; lds[i] = run; run += v; }
        blockSums[blockIdx.x] = run;
    }
    __syncthreads();
    int offs = lds[t];
    #pragma unroll
    for (int j = 0; j < 8; ++j) {
        int idx = base + t * 8 + j;
        if (idx < N_NODES) out[idx] = offs + local[j];
    }
}

__global__ void k_scan2(int* blockSums, int nb, int* rowptr) {
    int run = 0;
    for (int i = 0; i < nb; ++i) { int v = blockSums[i]; blockSums[i] = run; run += v; }
    rowptr[N_NODES] = N_EDGES;
}

__global__ __launch_bounds__(256) void k_scan3(int* rowptr, const int* __restrict__ blockSums) {
    int idx = blockIdx.x * 256 + threadIdx.x;
    if (idx < N_NODES) rowptr[idx] += blockSums[idx >> 11];
}

__global__ __launch_bounds__(256) void k_scatter(const int* __restrict__ src, const int* __restrict__ dst,
                                                 const int* __restrict__ rowptr, int* cursor,
                                                 int* __restrict__ csr_src) {
    int e = blockIdx.x * 256 + threadIdx.x;
    if (e >= N_EDGES) return;
    int d = dst[e];
    int pos = rowptr[d] + atomicAdd(&cursor[d], 1);
    csr_src[pos] = src[e];
}

__global__ __launch_bounds__(256) void k_dis(const int* __restrict__ rowptr, float* dis) {
    int n = blockIdx.x * 256 + threadIdx.x;
    if (n < N_NODES) {
        float deg = (float)(rowptr[n + 1] - rowptr[n]);
        dis[n] = rsqrtf(deg + 1.0f);
    }
}

// ---------- GEMM with W cached in LDS ----------
// out[M,Nc] = act(A[M,K] @ W[K,Nc] + bias); Nc in {32,128}; K*Nc <= 16384
__global__ __launch_bounds__(256) void k_gemm(const float* __restrict__ A,
                                              const float* __restrict__ W,
                                              const float* __restrict__ bias,
                                              float* __restrict__ out,
                                              int M, int K, int Nc, int act) {
    __shared__ float w_lds[16384];
    int tot = K * Nc;
    for (int i = threadIdx.x * 4; i < tot; i += 1024)
        *reinterpret_cast<float4*>(&w_lds[i]) = *reinterpret_cast<const float4*>(&W[i]);
    __syncthreads();
    int tpr = Nc >> 2;              // threads per row
    int rpb = 256 / tpr;            // rows per block
    int row = blockIdx.x * rpb + threadIdx.x / tpr;
    int c4 = (threadIdx.x % tpr) << 2;
    if (row >= M) return;
    const float* a = A + (size_t)row * K;
    float acc0 = 0.f, acc1 = 0.f, acc2 = 0.f, acc3 = 0.f;
    #pragma unroll 4
    for (int k = 0; k < K; ++k) {
        float av = a[k];
        float4 w = *reinterpret_cast<const float4*>(&w_lds[k * Nc + c4]);
        acc0 = fmaf(av, w.x, acc0);
        acc1 = fmaf(av, w.y, acc1);
        acc2 = fmaf(av, w.z, acc2);
        acc3 = fmaf(av, w.w, acc3);
    }
    if (bias) {
        acc0 += bias[c4 + 0]; acc1 += bias[c4 + 1];
        acc2 += bias[c4 + 2]; acc3 += bias[c4 + 3];
    }
    if (act) {
        acc0 = tanhf(acc0); acc1 = tanhf(acc1);
        acc2 = tanhf(acc2); acc3 = tanhf(acc3);
    }
    *reinterpret_cast<float4*>(&out[(size_t)row * Nc + c4]) =
        make_float4(acc0, acc1, acc2, acc3);
}

// ---------- GCN fused agg+combine (CSR, no atomics) ----------
// one wave per node; lane owns cols (lane, lane+64)
// out = tanh(dis[n]*sum_e(hW[src]*dis[src]) + hW[n]*dis[n]^2 + b)
__global__ __launch_bounds__(256) void k_gcn_fused(const int* __restrict__ rowptr,
                                                   const int* __restrict__ csr_src,
                                                   const float* __restrict__ hW,
                                                   const float* __restrict__ dis,
                                                   const float* __restrict__ bias,
                                                   float* __restrict__ out) {
    int wv = threadIdx.x >> 6, lane = threadIdx.x & 63;
    for (int n = blockIdx.x * 4 + wv; n < N_NODES; n += gridDim.x * 4) {
        int beg = rowptr[n], end = rowptr[n + 1];
        float a0 = 0.f, a1 = 0.f;
        for (int e = beg; e < end; ++e) {
            int s = csr_src[e];
            float ds = dis[s];
            const float* hp = &hW[(size_t)s * H];
            a0 = fmaf(hp[lane], ds, a0);
            a1 = fmaf(hp[64 + lane], ds, a1);
        }
        float dn = dis[n], dn2 = dn * dn;
        const float* hn = &hW[(size_t)n * H];
        out[(size_t)n * H + lane]      = tanhf(dn * a0 + hn[lane] * dn2 + bias[lane]);
        out[(size_t)n * H + 64 + lane] = tanhf(dn * a1 + hn[64 + lane] * dn2 + bias[64 + lane]);
    }
}

// ---------- EdgeConv fused (CSR, We2 in LDS, register max, no atomics) ----------
// one wave per node: m = max_e ( relu(U[n]+V[src]) @ We2 ); out = tanh(m+be2) (0 if no edges)
__global__ __launch_bounds__(256) void k_edge_csr(const int* __restrict__ rowptr,
                                                  const int* __restrict__ csr_src,
                                                  const float* __restrict__ U,
                                                  const float* __restrict__ V,
                                                  const float* __restrict__ We2g,
                                                  const float* __restrict__ be2,
                                                  float* __restrict__ out) {
    __shared__ float w_l[16384];    // We2 (64 KB)
    __shared__ float t_l[4][H];     // per-wave t vector
    for (int i = threadIdx.x * 4; i < 16384; i += 1024)
        *reinterpret_cast<float4*>(&w_l[i]) = *reinterpret_cast<const float4*>(&We2g[i]);
    __syncthreads();
    int wv = threadIdx.x >> 6, lane = threadIdx.x & 63;
    for (int n = blockIdx.x * 4 + wv; n < N_NODES; n += gridDim.x * 4) {
        int beg = rowptr[n], end = rowptr[n + 1];
        float u0 = U[(size_t)n * H + lane];
        float u1 = U[(size_t)n * H + 64 + lane];
        float m0 = -INFINITY, m1 = -INFINITY;
        for (int e = beg; e < end; ++e) {
            int s = csr_src[e];
            const float* vp = &V[(size_t)s * H];
            t_l[wv][lane]      = fmaxf(u0 + vp[lane], 0.f);
            t_l[wv][64 + lane] = fmaxf(u1 + vp[64 + lane], 0.f);
            __builtin_amdgcn_wave_barrier();   // per-wave LDS: lockstep + in-order DS pipe
            float acc0 = 0.f, acc1 = 0.f;
            #pragma unroll 4
            for (int k = 0; k < H; k += 4) {
                float4 tv = *reinterpret_cast<const float4*>(&t_l[wv][k]);
                acc0 = fmaf(tv.x, w_l[(k + 0) * H + lane], acc0);
                acc1 = fmaf(tv.x, w_l[(k + 0) * H + 64 + lane], acc1);
                acc0 = fmaf(tv.y, w_l[(k + 1) * H + lane], acc0);
                acc1 = fmaf(tv.y, w_l[(k + 1) * H + 64 + lane], acc1);
                acc0 = fmaf(tv.z, w_l[(k + 2) * H + lane], acc0);
                acc1 = fmaf(tv.z, w_l[(k + 2) * H + 64 + lane], acc1);
                acc0 = fmaf(tv.w, w_l[(k + 3) * H + lane], acc0);
                acc1 = fmaf(tv.w, w_l[(k + 3) * H + 64 + lane], acc1);
            }
            __builtin_amdgcn_wave_barrier();
            m0 = fmaxf(m0, acc0);
            m1 = fmaxf(m1, acc1);
        }
        bool hasE = end > beg;
        float r0 = hasE ? (m0 + be2[lane]) : 0.f;
        float r1 = hasE ? (m1 + be2[64 + lane]) : 0.f;
        out[(size_t)n * H + lane]      = tanhf(r0);
        out[(size_t)n * H + 64 + lane] = tanhf(r1);
    }
}

// ---------- final per-node scalar + batch-mean pooling ----------
__global__ __launch_bounds__(256) void k_pool(const float* __restrict__ f2,
                                              const float* __restrict__ Wf3,
                                              const float* __restrict__ bf3,
                                              const int* __restrict__ batch,
                                              float* pooled, float* counts) {
    __shared__ float lp[G_GRAPHS];
    __shared__ float lc[G_GRAPHS];
    int tid = threadIdx.x;
    if (tid < G_GRAPHS) { lp[tid] = 0.f; lc[tid] = 0.f; }
    __syncthreads();
    int n = blockIdx.x * 256 + tid;
    if (n < N_NODES) {
        float s = bf3[0];
        #pragma unroll
        for (int k = 0; k < 32; ++k) s = fmaf(f2[(size_t)n * 32 + k], Wf3[k], s);
        int b = batch[n];
        atomicAdd(&lp[b], s);
        atomicAdd(&lc[b], 1.0f);
    }
    __syncthreads();
    if (tid < G_GRAPHS && lc[tid] > 0.f) {
        atomicAdd(&pooled[tid], lp[tid]);
        atomicAdd(&counts[tid], lc[tid]);
    }
}

__global__ __launch_bounds__(64) void k_final(const float* pooled, const float* counts,
                                              void* out, const int* __restrict__ flag) {
    int g = threadIdx.x;
    if (g < G_GRAPHS) {
        float v = pooled[g] / fmaxf(counts[g], 1.0f);
        float s = 1.0f / (1.0f + expf(-v));
        if (*flag) ((__hip_bfloat16*)out)[g] = __float2bfloat16(s);
        else       ((float*)out)[g] = s;
    }
}

extern "C" void kernel_launch(void* const* d_in, const int* in_sizes, int n_in,
                              void* d_out, int out_size, void* d_ws, size_t ws_size,
                              hipStream_t stream) {
    const int* ei    = (const int*)d_in[1];
    const int* src   = ei;
    const int* dst   = ei + N_EDGES;
    const int* batch = (const int*)d_in[2];

    float* ws = (float*)d_ws;
    size_t off = 0;
    auto alloc = [&](size_t n) { float* p = ws + off; off += n; return p; };

    const size_t NH = (size_t)N_NODES * H;
    float* bufA   = alloc(NH);
    float* bufB   = alloc(NH);
    float* bufC   = alloc(NH);          // also holds xf before first GEMM; f2 at end
    float* dis    = alloc(N_NODES);
    float* pooled = alloc(G_GRAPHS);
    float* counts = alloc(G_GRAPHS);
    int*   flag   = (int*)alloc(1);
    int*   rowptr = (int*)alloc(N_NODES + 1);
    int*   cursor = (int*)alloc(N_NODES);
    int*   csrsrc = (int*)alloc(N_EDGES);
    int*   bsums  = (int*)alloc(32);

    float* W1  = alloc(F_IN * H);
    float* b1  = alloc(H);
    float* W2  = alloc(HH);
    float* b2  = alloc(H);
    float* We1 = alloc(2 * HH);         // first half becomes (We1a - We1b) in place
    float* be1 = alloc(H);
    float* We2 = alloc(HH);
    float* be2 = alloc(H);
    float* Wf1 = alloc(HH);
    float* bf1 = alloc(H);
    float* Wf2 = alloc(H * 32);
    float* bf2 = alloc(32);
    float* Wf3 = alloc(32);
    float* bf3 = alloc(1);

    const int eB   = (N_EDGES + 255) / 256;
    const int nB   = (N_NODES + 255) / 256;
    const int scanB = (N_NODES + 2047) / 2048;     // 25
    const int gemmB128 = (N_NODES + 7) / 8;        // rpb=8 for Nc=128
    const int gemmB32  = (N_NODES + 31) / 32;      // rpb=32 for Nc=32

    // dtype detection + input conversion
    k_detect<<<1, 256, 0, stream>>>((const unsigned*)d_in[0], flag);
    auto cvt = [&](int idx, float* dstp, int n) {
        k_cvt<<<(n + 255) / 256, 256, 0, stream>>>(d_in[idx], dstp, n, flag);
    };
    float* xf = bufC;                    // x lives in bufC until after GCN1 GEMM
    cvt(0,  xf,  N_NODES * F_IN);
    cvt(3,  W1,  F_IN * H);
    cvt(4,  b1,  H);
    cvt(5,  W2,  HH);
    cvt(6,  b2,  H);
    cvt(7,  We1, 2 * HH);
    cvt(8,  be1, H);
    cvt(9,  We2, HH);
    cvt(10, be2, H);
    cvt(11, Wf1, HH);
    cvt(12, bf1, H);
    cvt(13, Wf2, H * 32);
    cvt(14, bf2, 32);
    cvt(15, Wf3, 32);
    cvt(16, bf3, 1);
    k_sub<<<(HH + 255) / 256, 256, 0, stream>>>(We1);

    // CSR build (sorted by dst)
    k_zero<<<nB, 256, 0, stream>>>((float*)cursor, N_NODES);
    k_hist<<<eB, 256, 0, stream>>>(dst, cursor);
    k_scan1<<<scanB, 256, 0, stream>>>(cursor, rowptr, bsums);
    k_scan2<<<1, 1, 0, stream>>>(bsums, scanB, rowptr);
    k_scan3<<<nB, 256, 0, stream>>>(rowptr, bsums);
    k_zero<<<nB, 256, 0, stream>>>((float*)cursor, N_NODES);
    k_scatter<<<eB, 256, 0, stream>>>(src, dst, rowptr, cursor, csrsrc);
    k_dis<<<nB, 256, 0, stream>>>(rowptr, dis);
    k_zero<<<1, 256, 0, stream>>>(pooled, 2 * G_GRAPHS);

    // GCN1: hW = x @ W1 -> bufB ; fused agg+combine -> bufA
    k_gemm<<<gemmB128, 256, 0, stream>>>(xf, W1, nullptr, bufB, N_NODES, F_IN, H, 0);
    k_gcn_fused<<<512, 256, 0, stream>>>(rowptr, csrsrc, bufB, dis, b1, bufA);

    for (int iter = 0; iter < 3; ++iter) {
        // EdgeConv: U = A@(We1a-We1b)+be1 -> bufB ; V = A@We1b -> bufC
        k_gemm<<<gemmB128, 256, 0, stream>>>(bufA, We1, be1, bufB, N_NODES, H, H, 0);
        k_gemm<<<gemmB128, 256, 0, stream>>>(bufA, We1 + HH, nullptr, bufC, N_NODES, H, H, 0);
        k_edge_csr<<<1024, 256, 0, stream>>>(rowptr, csrsrc, bufB, bufC, We2, be2, bufA);
        if (iter < 2) {
            k_gemm<<<gemmB128, 256, 0, stream>>>(bufA, W2, nullptr, bufB, N_NODES, H, H, 0);
            k_gcn_fused<<<512, 256, 0, stream>>>(rowptr, csrsrc, bufB, dis, b2, bufA);
        }
    }

    // final MLP
    k_gemm<<<gemmB128, 256, 0, stream>>>(bufA, Wf1, bf1, bufB, N_NODES, H, H, 1);
    k_gemm<<<gemmB32, 256, 0, stream>>>(bufB, Wf2, bf2, bufC, N_NODES, H, 32, 1);
    k_pool<<<nB, 256, 0, stream>>>(bufC, Wf3, bf3, batch, pooled, counts);
    k_final<<<1, 64, 0, stream>>>(pooled, counts, d_out, flag);
}

// Round 4
// 2610.665 us; speedup vs baseline: 5.3999x; 2.0002x over previous
//
#include <hip/hip_runtime.h>
#include <hip/hip_bf16.h>

#define N_NODES 50000
#define N_EDGES 800000
#define F_IN 9
#define H 128
#define G_GRAPHS 64
#define HH (H * H)

typedef short bf16x8 __attribute__((ext_vector_type(8)));
typedef float f32x4 __attribute__((ext_vector_type(4)));

static __device__ inline short f2b(float f) {
    __hip_bfloat16 h = __float2bfloat16(f);
    return *reinterpret_cast<short*>(&h);
}

// ---------- dtype detection ----------
__global__ __launch_bounds__(256) void k_detect(const unsigned* __restrict__ x, int* flag) {
    __shared__ int cnt;
    if (threadIdx.x == 0) cnt = 0;
    __syncthreads();
    unsigned u = x[threadIdx.x];
    int e = (u >> 7) & 0xFF;
    if (e >= 0x70 && e <= 0x83) atomicAdd(&cnt, 1);
    __syncthreads();
    if (threadIdx.x == 0) *flag = (cnt >= 128) ? 1 : 0;
}

__global__ __launch_bounds__(256) void k_cvt(const void* __restrict__ src, float* __restrict__ dst,
                                             int n, const int* __restrict__ flag) {
    int i = blockIdx.x * 256 + threadIdx.x;
    if (i >= n) return;
    if (*flag)
        dst[i] = __bfloat162float(((const __hip_bfloat16*)src)[i]);
    else
        dst[i] = ((const float*)src)[i];
}

__global__ __launch_bounds__(256) void k_zero(float* p, int n) {
    int i = blockIdx.x * 256 + threadIdx.x;
    if (i < n) p[i] = 0.f;
}

__global__ __launch_bounds__(256) void k_sub(float* w) {
    int i = blockIdx.x * 256 + threadIdx.x;
    if (i < HH) w[i] -= w[HH + i];
}

// ---------- We2 -> bf16 MFMA B-fragment layout ----------
// We2f[((kc*8+ct)*64+lane)*8 + j] = bf16(We2[kc*32+(lane>>4)*8+j][ct*16+(lane&15)])
__global__ __launch_bounds__(256) void k_prep_we2(const float* __restrict__ We2,
                                                  short* __restrict__ We2f) {
    int tid = blockIdx.x * 256 + threadIdx.x;   // 2048 total
    int kc = tid >> 9, ct = (tid >> 6) & 7, lane = tid & 63;
    int kb = kc * 32 + (lane >> 4) * 8;
    int col = ct * 16 + (lane & 15);
    #pragma unroll
    for (int j = 0; j < 8; ++j)
        We2f[tid * 8 + j] = f2b(We2[(kb + j) * H + col]);
}

// ---------- CSR build ----------
__global__ __launch_bounds__(256) void k_hist(const int* __restrict__ dst, int* cnt) {
    int e = blockIdx.x * 256 + threadIdx.x;
    if (e < N_EDGES) atomicAdd(&cnt[dst[e]], 1);
}

__global__ __launch_bounds__(256) void k_scan1(const int* __restrict__ deg, int* __restrict__ out,
                                               int* __restrict__ blockSums) {
    __shared__ int lds[256];
    int base = blockIdx.x * 2048;
    int t = threadIdx.x;
    int local[8];
    int s = 0;
    #pragma unroll
    for (int j = 0; j < 8; ++j) {
        int idx = base + t * 8 + j;
        int v = (idx < N_NODES) ? deg[idx] : 0;
        local[j] = s;
        s += v;
    }
    lds[t] = s;
    __syncthreads();
    if (t == 0) {
        int run = 0;
        for (int i = 0; i < 256; ++i) { int v = lds[i]; lds[i] = run; run += v; }
        blockSums[blockIdx.x] = run;
    }
    __syncthreads();
    int offs = lds[t];
    #pragma unroll
    for (int j = 0; j < 8; ++j) {
        int idx = base + t * 8 + j;
        if (idx < N_NODES) out[idx] = offs + local[j];
    }
}

__global__ void k_scan2(int* blockSums, int nb, int* rowptr) {
    int run = 0;
    for (int i = 0; i < nb; ++i) { int v = blockSums[i]; blockSums[i] = run; run += v; }
    rowptr[N_NODES] = N_EDGES;
}

__global__ __launch_bounds__(256) void k_scan3(int* rowptr, const int* __restrict__ blockSums) {
    int idx = blockIdx.x * 256 + threadIdx.x;
    if (idx < N_NODES) rowptr[idx] += blockSums[idx >> 11];
}

__global__ __launch_bounds__(256) void k_scatter(const int* __restrict__ src, const int* __restrict__ dst,
                                                 const int* __restrict__ rowptr, int* cursor,
                                                 int* __restrict__ csr_src) {
    int e = blockIdx.x * 256 + threadIdx.x;
    if (e >= N_EDGES) return;
    int d = dst[e];
    int pos = rowptr[d] + atomicAdd(&cursor[d], 1);
    csr_src[pos] = src[e];
}

__global__ __launch_bounds__(256) void k_dis(const int* __restrict__ rowptr, float* dis) {
    int n = blockIdx.x * 256 + threadIdx.x;
    if (n < N_NODES) {
        float deg = (float)(rowptr[n + 1] - rowptr[n]);
        dis[n] = rsqrtf(deg + 1.0f);
    }
}

// ---------- GEMM with W cached in LDS ----------
__global__ __launch_bounds__(256) void k_gemm(const float* __restrict__ A,
                                              const float* __restrict__ W,
                                              const float* __restrict__ bias,
                                              float* __restrict__ out,
                                              int M, int K, int Nc, int act) {
    __shared__ float w_lds[16384];
    int tot = K * Nc;
    for (int i = threadIdx.x * 4; i < tot; i += 1024)
        *reinterpret_cast<float4*>(&w_lds[i]) = *reinterpret_cast<const float4*>(&W[i]);
    __syncthreads();
    int tpr = Nc >> 2;
    int rpb = 256 / tpr;
    int row = blockIdx.x * rpb + threadIdx.x / tpr;
    int c4 = (threadIdx.x % tpr) << 2;
    if (row >= M) return;
    const float* a = A + (size_t)row * K;
    float acc0 = 0.f, acc1 = 0.f, acc2 = 0.f, acc3 = 0.f;
    #pragma unroll 4
    for (int k = 0; k < K; ++k) {
        float av = a[k];
        float4 w = *reinterpret_cast<const float4*>(&w_lds[k * Nc + c4]);
        acc0 = fmaf(av, w.x, acc0);
        acc1 = fmaf(av, w.y, acc1);
        acc2 = fmaf(av, w.z, acc2);
        acc3 = fmaf(av, w.w, acc3);
    }
    if (bias) {
        acc0 += bias[c4 + 0]; acc1 += bias[c4 + 1];
        acc2 += bias[c4 + 2]; acc3 += bias[c4 + 3];
    }
    if (act) {
        acc0 = tanhf(acc0); acc1 = tanhf(acc1);
        acc2 = tanhf(acc2); acc3 = tanhf(acc3);
    }
    *reinterpret_cast<float4*>(&out[(size_t)row * Nc + c4]) =
        make_float4(acc0, acc1, acc2, acc3);
}

// ---------- GCN fused agg+combine (CSR, no atomics) ----------
__global__ __launch_bounds__(256) void k_gcn_fused(const int* __restrict__ rowptr,
                                                   const int* __restrict__ csr_src,
                                                   const float* __restrict__ hW,
                                                   const float* __restrict__ dis,
                                                   const float* __restrict__ bias,
                                                   float* __restrict__ out) {
    int wv = threadIdx.x >> 6, lane = threadIdx.x & 63;
    for (int n = blockIdx.x * 4 + wv; n < N_NODES; n += gridDim.x * 4) {
        int beg = rowptr[n], end = rowptr[n + 1];
        float a0 = 0.f, a1 = 0.f;
        for (int e = beg; e < end; ++e) {
            int s = csr_src[e];
            float ds = dis[s];
            const float* hp = &hW[(size_t)s * H];
            a0 = fmaf(hp[lane], ds, a0);
            a1 = fmaf(hp[64 + lane], ds, a1);
        }
        float dn = dis[n], dn2 = dn * dn;
        const float* hn = &hW[(size_t)n * H];
        out[(size_t)n * H + lane]      = tanhf(dn * a0 + hn[lane] * dn2 + bias[lane]);
        out[(size_t)n * H + 64 + lane] = tanhf(dn * a1 + hn[64 + lane] * dn2 + bias[64 + lane]);
    }
}

// ---------- EdgeConv via MFMA (CSR, We2 bf16 frags in LDS, masked register max) ----------
// one wave per node; T[16,128] tiles, acc = T @ We2 via mfma_f32_16x16x32_bf16
__global__ __launch_bounds__(256) void k_edge_mfma(const int* __restrict__ rowptr,
                                                   const int* __restrict__ csr_src,
                                                   const float* __restrict__ U,
                                                   const float* __restrict__ V,
                                                   const short* __restrict__ We2f,
                                                   const float* __restrict__ be2,
                                                   float* __restrict__ out) {
    __shared__ short wl[16384];     // 32 KB bf16 B-fragments
    for (int i = threadIdx.x * 8; i < 16384; i += 2048)
        *reinterpret_cast<f32x4*>(&wl[i]) = *reinterpret_cast<const f32x4*>(&We2f[i]);
    __syncthreads();
    int wv = threadIdx.x >> 6, lane = threadIdx.x & 63;
    int er = lane & 15;          // A-row / D-col within tile
    int kg = lane >> 4;          // k-group
    int kseg = kg * 8;
    const f32x4 vzero = {0.f, 0.f, 0.f, 0.f};
    const f32x4 vninf = {-INFINITY, -INFINITY, -INFINITY, -INFINITY};
    for (int n = blockIdx.x * 4 + wv; n < N_NODES; n += gridDim.x * 4) {
        int beg = rowptr[n], end = rowptr[n + 1];
        int deg = end - beg;
        float cm[8] = {0, 0, 0, 0, 0, 0, 0, 0};
        if (deg > 0) {
            // preload U[n] k-slices for this lane
            f32x4 u0[4], u1[4];
            #pragma unroll
            for (int kc = 0; kc < 4; ++kc) {
                const float* up = &U[(size_t)n * H + kc * 32 + kseg];
                u0[kc] = *reinterpret_cast<const f32x4*>(up);
                u1[kc] = *reinterpret_cast<const f32x4*>(up + 4);
            }
            f32x4 m[8];
            #pragma unroll
            for (int ct = 0; ct < 8; ++ct) m[ct] = vninf;
            int ntiles = (deg + 15) >> 4;
            for (int t = 0; t < ntiles; ++t) {
                int ei = beg + t * 16 + er;
                int s = csr_src[ei < end ? ei : end - 1];
                // build A fragments: T[er][k] = relu(U[n][k] + V[s][k])
                bf16x8 af[4];
                #pragma unroll
                for (int kc = 0; kc < 4; ++kc) {
                    const float* vp = &V[(size_t)s * H + kc * 32 + kseg];
                    f32x4 v0 = *reinterpret_cast<const f32x4*>(vp);
                    f32x4 v1 = *reinterpret_cast<const f32x4*>(vp + 4);
                    #pragma unroll
                    for (int j = 0; j < 4; ++j) {
                        af[kc][j]     = f2b(fmaxf(u0[kc][j] + v0[j], 0.f));
                        af[kc][4 + j] = f2b(fmaxf(u1[kc][j] + v1[j], 0.f));
                    }
                }
                // 32 MFMAs: acc[ct] += A(k-chunk kc) * B(kc, ct)
                f32x4 acc[8];
                #pragma unroll
                for (int ct = 0; ct < 8; ++ct) acc[ct] = vzero;
                #pragma unroll
                for (int kc = 0; kc < 4; ++kc) {
                    #pragma unroll
                    for (int ct = 0; ct < 8; ++ct) {
                        bf16x8 bf = *reinterpret_cast<const bf16x8*>(&wl[((kc * 8 + ct) * 64 + lane) * 8]);
                        acc[ct] = __builtin_amdgcn_mfma_f32_16x16x32_bf16(af[kc], bf, acc[ct], 0, 0, 0);
                    }
                }
                // masked max-merge over this tile's rows (row = kg*4 + r)
                int rowbase = t * 16 + kg * 4;
                #pragma unroll
                for (int r = 0; r < 4; ++r) {
                    if (rowbase + r < deg) {
                        #pragma unroll
                        for (int ct = 0; ct < 8; ++ct)
                            m[ct][r] = fmaxf(m[ct][r], acc[ct][r]);
                    }
                }
            }
            // reduce: per-lane 4 rows, then across the 4 k-groups
            #pragma unroll
            for (int ct = 0; ct < 8; ++ct) {
                float v = fmaxf(fmaxf(m[ct][0], m[ct][1]), fmaxf(m[ct][2], m[ct][3]));
                v = fmaxf(v, __shfl_xor(v, 16));
                v = fmaxf(v, __shfl_xor(v, 32));
                cm[ct] = v;
            }
        }
        // write: each lane writes cols for ct = kg*2 + {0,1}
        #pragma unroll
        for (int q = 0; q < 2; ++q) {
            int ct = kg * 2 + q;
            int col = ct * 16 + er;
            float val = (deg > 0) ? (cm[ct] + be2[col]) : 0.f;
            out[(size_t)n * H + col] = tanhf(val);
        }
    }
}

// ---------- final per-node scalar + batch-mean pooling ----------
__global__ __launch_bounds__(256) void k_pool(const float* __restrict__ f2,
                                              const float* __restrict__ Wf3,
                                              const float* __restrict__ bf3,
                                              const int* __restrict__ batch,
                                              float* pooled, float* counts) {
    __shared__ float lp[G_GRAPHS];
    __shared__ float lc[G_GRAPHS];
    int tid = threadIdx.x;
    if (tid < G_GRAPHS) { lp[tid] = 0.f; lc[tid] = 0.f; }
    __syncthreads();
    int n = blockIdx.x * 256 + tid;
    if (n < N_NODES) {
        float s = bf3[0];
        #pragma unroll
        for (int k = 0; k < 32; ++k) s = fmaf(f2[(size_t)n * 32 + k], Wf3[k], s);
        int b = batch[n];
        atomicAdd(&lp[b], s);
        atomicAdd(&lc[b], 1.0f);
    }
    __syncthreads();
    if (tid < G_GRAPHS && lc[tid] > 0.f) {
        atomicAdd(&pooled[tid], lp[tid]);
        atomicAdd(&counts[tid], lc[tid]);
    }
}

__global__ __launch_bounds__(64) void k_final(const float* pooled, const float* counts,
                                              void* out, const int* __restrict__ flag) {
    int g = threadIdx.x;
    if (g < G_GRAPHS) {
        float v = pooled[g] / fmaxf(counts[g], 1.0f);
        float s = 1.0f / (1.0f + expf(-v));
        if (*flag) ((__hip_bfloat16*)out)[g] = __float2bfloat16(s);
        else       ((float*)out)[g] = s;
    }
}

extern "C" void kernel_launch(void* const* d_in, const int* in_sizes, int n_in,
                              void* d_out, int out_size, void* d_ws, size_t ws_size,
                              hipStream_t stream) {
    const int* ei    = (const int*)d_in[1];
    const int* src   = ei;
    const int* dst   = ei + N_EDGES;
    const int* batch = (const int*)d_in[2];

    float* ws = (float*)d_ws;
    size_t off = 0;
    auto alloc = [&](size_t n) { float* p = ws + off; off += n; return p; };

    const size_t NH = (size_t)N_NODES * H;
    float* bufA   = alloc(NH);
    float* bufB   = alloc(NH);
    float* bufC   = alloc(NH);
    float* dis    = alloc(N_NODES);
    float* pooled = alloc(G_GRAPHS);
    float* counts = alloc(G_GRAPHS);
    int*   flag   = (int*)alloc(1);
    int*   rowptr = (int*)alloc(N_NODES + 1);
    int*   cursor = (int*)alloc(N_NODES);
    int*   csrsrc = (int*)alloc(N_EDGES);
    int*   bsums  = (int*)alloc(32);

    float* W1  = alloc(F_IN * H);
    float* b1  = alloc(H);
    float* W2  = alloc(HH);
    float* b2  = alloc(H);
    float* We1 = alloc(2 * HH);
    float* be1 = alloc(H);
    float* We2 = alloc(HH);
    float* be2 = alloc(H);
    float* Wf1 = alloc(HH);
    float* bf1 = alloc(H);
    float* Wf2 = alloc(H * 32);
    float* bf2 = alloc(32);
    float* Wf3 = alloc(32);
    float* bf3 = alloc(1);
    short* We2f = (short*)alloc(8192);   // 16384 bf16

    const int eB   = (N_EDGES + 255) / 256;
    const int nB   = (N_NODES + 255) / 256;
    const int scanB = (N_NODES + 2047) / 2048;
    const int gemmB128 = (N_NODES + 7) / 8;
    const int gemmB32  = (N_NODES + 31) / 32;

    k_detect<<<1, 256, 0, stream>>>((const unsigned*)d_in[0], flag);
    auto cvt = [&](int idx, float* dstp, int n) {
        k_cvt<<<(n + 255) / 256, 256, 0, stream>>>(d_in[idx], dstp, n, flag);
    };
    float* xf = bufC;
    cvt(0,  xf,  N_NODES * F_IN);
    cvt(3,  W1,  F_IN * H);
    cvt(4,  b1,  H);
    cvt(5,  W2,  HH);
    cvt(6,  b2,  H);
    cvt(7,  We1, 2 * HH);
    cvt(8,  be1, H);
    cvt(9,  We2, HH);
    cvt(10, be2, H);
    cvt(11, Wf1, HH);
    cvt(12, bf1, H);
    cvt(13, Wf2, H * 32);
    cvt(14, bf2, 32);
    cvt(15, Wf3, 32);
    cvt(16, bf3, 1);
    k_sub<<<(HH + 255) / 256, 256, 0, stream>>>(We1);
    k_prep_we2<<<8, 256, 0, stream>>>(We2, We2f);

    // CSR build (sorted by dst)
    k_zero<<<nB, 256, 0, stream>>>((float*)cursor, N_NODES);
    k_hist<<<eB, 256, 0, stream>>>(dst, cursor);
    k_scan1<<<scanB, 256, 0, stream>>>(cursor, rowptr, bsums);
    k_scan2<<<1, 1, 0, stream>>>(bsums, scanB, rowptr);
    k_scan3<<<nB, 256, 0, stream>>>(rowptr, bsums);
    k_zero<<<nB, 256, 0, stream>>>((float*)cursor, N_NODES);
    k_scatter<<<eB, 256, 0, stream>>>(src, dst, rowptr, cursor, csrsrc);
    k_dis<<<nB, 256, 0, stream>>>(rowptr, dis);
    k_zero<<<1, 256, 0, stream>>>(pooled, 2 * G_GRAPHS);

    // GCN1
    k_gemm<<<gemmB128, 256, 0, stream>>>(xf, W1, nullptr, bufB, N_NODES, F_IN, H, 0);
    k_gcn_fused<<<1024, 256, 0, stream>>>(rowptr, csrsrc, bufB, dis, b1, bufA);

    for (int iter = 0; iter < 3; ++iter) {
        k_gemm<<<gemmB128, 256, 0, stream>>>(bufA, We1, be1, bufB, N_NODES, H, H, 0);
        k_gemm<<<gemmB128, 256, 0, stream>>>(bufA, We1 + HH, nullptr, bufC, N_NODES, H, H, 0);
        k_edge_mfma<<<1024, 256, 0, stream>>>(rowptr, csrsrc, bufB, bufC, We2f, be2, bufA);
        if (iter < 2) {
            k_gemm<<<gemmB128, 256, 0, stream>>>(bufA, W2, nullptr, bufB, N_NODES, H, H, 0);
            k_gcn_fused<<<1024, 256, 0, stream>>>(rowptr, csrsrc, bufB, dis, b2, bufA);
        }
    }

    // final MLP
    k_gemm<<<gemmB128, 256, 0, stream>>>(bufA, Wf1, bf1, bufB, N_NODES, H, H, 1);
    k_gemm<<<gemmB32, 256, 0, stream>>>(bufB, Wf2, bf2, bufC, N_NODES, H, 32, 1);
    k_pool<<<nB, 256, 0, stream>>>(bufC, Wf3, bf3, batch, pooled, counts);
    k_final<<<1, 64, 0, stream>>>(pooled, counts, d_out, flag);
}

// Round 5
// 1063.797 us; speedup vs baseline: 13.2518x; 2.4541x over previous
//
#include <hip/hip_runtime.h>
#include <hip/hip_bf16.h>

#define N_NODES 50000
#define N_EDGES 800000
#define F_IN 9
#define H 128
#define G_GRAPHS 64
#define HH (H * H)

typedef short bf16x8 __attribute__((ext_vector_type(8)));
typedef float f32x4 __attribute__((ext_vector_type(4)));

static __device__ inline short f2b(float f) {
    __hip_bfloat16 h = __float2bfloat16(f);
    return *reinterpret_cast<short*>(&h);
}
static __device__ inline float b2f(short s) {
    unsigned u = ((unsigned)(unsigned short)s) << 16;
    return __uint_as_float(u);
}

// ---------- dtype detection ----------
__global__ __launch_bounds__(256) void k_detect(const unsigned* __restrict__ x, int* flag) {
    __shared__ int cnt;
    if (threadIdx.x == 0) cnt = 0;
    __syncthreads();
    unsigned u = x[threadIdx.x];
    int e = (u >> 7) & 0xFF;
    if (e >= 0x70 && e <= 0x83) atomicAdd(&cnt, 1);
    __syncthreads();
    if (threadIdx.x == 0) *flag = (cnt >= 128) ? 1 : 0;
}

__global__ __launch_bounds__(256) void k_cvt(const void* __restrict__ src, float* __restrict__ dst,
                                             int n, const int* __restrict__ flag) {
    int i = blockIdx.x * 256 + threadIdx.x;
    if (i >= n) return;
    if (*flag)
        dst[i] = __bfloat162float(((const __hip_bfloat16*)src)[i]);
    else
        dst[i] = ((const float*)src)[i];
}

__global__ __launch_bounds__(256) void k_zero(float* p, int n) {
    int i = blockIdx.x * 256 + threadIdx.x;
    if (i < n) p[i] = 0.f;
}

__global__ __launch_bounds__(256) void k_sub(float* w) {
    int i = blockIdx.x * 256 + threadIdx.x;
    if (i < HH) w[i] -= w[HH + i];
}

// ---------- W[128,NT*16] f32 -> bf16 MFMA B-fragment table ----------
// Wf[((kc*NT+ct)*64+lane)*8 + j] = bf16(W[kc*32+(lane>>4)*8+j][ct*16+(lane&15)])
__global__ __launch_bounds__(256) void k_prep(const float* __restrict__ W,
                                              short* __restrict__ Wf, int NT) {
    int tid = blockIdx.x * 256 + threadIdx.x;
    int total = 4 * NT * 64;
    if (tid >= total) return;
    int kc = tid / (NT * 64);
    int ct = (tid / 64) % NT;
    int lane = tid & 63;
    int Nc = NT * 16;
    int kb = kc * 32 + (lane >> 4) * 8;
    int col = ct * 16 + (lane & 15);
    #pragma unroll
    for (int j = 0; j < 8; ++j)
        Wf[tid * 8 + j] = f2b(W[(kb + j) * Nc + col]);
}

// ---------- CSR build ----------
__global__ __launch_bounds__(256) void k_hist(const int* __restrict__ dst, int* cnt) {
    int e = blockIdx.x * 256 + threadIdx.x;
    if (e < N_EDGES) atomicAdd(&cnt[dst[e]], 1);
}

__global__ __launch_bounds__(256) void k_scan1(const int* __restrict__ deg, int* __restrict__ out,
                                               int* __restrict__ blockSums) {
    __shared__ int lds[256];
    int base = blockIdx.x * 2048;
    int t = threadIdx.x;
    int local[8];
    int s = 0;
    #pragma unroll
    for (int j = 0; j < 8; ++j) {
        int idx = base + t * 8 + j;
        int v = (idx < N_NODES) ? deg[idx] : 0;
        local[j] = s;
        s += v;
    }
    lds[t] = s;
    __syncthreads();
    if (t == 0) {
        int run = 0;
        for (int i = 0; i < 256; ++i) { int v = lds[i]; lds[i] = run; run += v; }
        blockSums[blockIdx.x] = run;
    }
    __syncthreads();
    int offs = lds[t];
    #pragma unroll
    for (int j = 0; j < 8; ++j) {
        int idx = base + t * 8 + j;
        if (idx < N_NODES) out[idx] = offs + local[j];
    }
}

__global__ void k_scan2(int* blockSums, int nb, int* rowptr) {
    int run = 0;
    for (int i = 0; i < nb; ++i) { int v = blockSums[i]; blockSums[i] = run; run += v; }
    rowptr[N_NODES] = N_EDGES;
}

__global__ __launch_bounds__(256) void k_scan3(int* rowptr, const int* __restrict__ blockSums) {
    int idx = blockIdx.x * 256 + threadIdx.x;
    if (idx < N_NODES) rowptr[idx] += blockSums[idx >> 11];
}

__global__ __launch_bounds__(256) void k_scatter(const int* __restrict__ src, const int* __restrict__ dst,
                                                 const int* __restrict__ rowptr, int* cursor,
                                                 int* __restrict__ csr_src) {
    int e = blockIdx.x * 256 + threadIdx.x;
    if (e >= N_EDGES) return;
    int d = dst[e];
    int pos = rowptr[d] + atomicAdd(&cursor[d], 1);
    csr_src[pos] = src[e];
}

__global__ __launch_bounds__(256) void k_dis(const int* __restrict__ rowptr, float* dis) {
    int n = blockIdx.x * 256 + threadIdx.x;
    if (n < N_NODES) {
        float deg = (float)(rowptr[n + 1] - rowptr[n]);
        dis[n] = rsqrtf(deg + 1.0f);
    }
}

// ---------- f32 GEMM (K*Nc <= 2048) with bf16 output; used for x@W1 ----------
__global__ __launch_bounds__(256) void k_gemm_f32bf(const float* __restrict__ A,
                                                    const float* __restrict__ W,
                                                    short* __restrict__ out,
                                                    int M, int K, int Nc) {
    __shared__ float w_lds[2048];
    int tot = K * Nc;
    for (int i = threadIdx.x * 4; i < tot; i += 1024)
        *reinterpret_cast<float4*>(&w_lds[i]) = *reinterpret_cast<const float4*>(&W[i]);
    __syncthreads();
    int tpr = Nc >> 2;
    int rpb = 256 / tpr;
    int row = blockIdx.x * rpb + threadIdx.x / tpr;
    int c4 = (threadIdx.x % tpr) << 2;
    if (row >= M) return;
    const float* a = A + (size_t)row * K;
    float acc0 = 0.f, acc1 = 0.f, acc2 = 0.f, acc3 = 0.f;
    for (int k = 0; k < K; ++k) {
        float av = a[k];
        float4 w = *reinterpret_cast<const float4*>(&w_lds[k * Nc + c4]);
        acc0 = fmaf(av, w.x, acc0);
        acc1 = fmaf(av, w.y, acc1);
        acc2 = fmaf(av, w.z, acc2);
        acc3 = fmaf(av, w.w, acc3);
    }
    short* op = &out[(size_t)row * Nc + c4];
    op[0] = f2b(acc0); op[1] = f2b(acc1); op[2] = f2b(acc2); op[3] = f2b(acc3);
}

// ---------- MFMA GEMM: out[M,NT*16] = act(A[M,128]bf16 @ W + bias), bf16 out ----------
template<int NT, int ACT>
__global__ __launch_bounds__(256) void k_gemm_mfma(const short* __restrict__ A,
                                                   const short* __restrict__ Wf,
                                                   const float* __restrict__ bias,
                                                   short* __restrict__ out, int M) {
    __shared__ short wl[4 * NT * 64 * 8];
    for (int i = threadIdx.x * 8; i < 4 * NT * 64 * 8; i += 2048)
        *reinterpret_cast<f32x4*>(&wl[i]) = *reinterpret_cast<const f32x4*>(&Wf[i]);
    __syncthreads();
    int wv = threadIdx.x >> 6, lane = threadIdx.x & 63;
    int er = lane & 15, kg = lane >> 4;
    int row0 = (blockIdx.x * 4 + wv) * 16;
    if (row0 >= M) return;
    bf16x8 af[4];
    #pragma unroll
    for (int kc = 0; kc < 4; ++kc)
        af[kc] = *reinterpret_cast<const bf16x8*>(&A[(size_t)(row0 + er) * H + kc * 32 + kg * 8]);
    f32x4 acc[NT];
    const f32x4 vzero = {0.f, 0.f, 0.f, 0.f};
    #pragma unroll
    for (int ct = 0; ct < NT; ++ct) acc[ct] = vzero;
    #pragma unroll
    for (int kc = 0; kc < 4; ++kc) {
        #pragma unroll
        for (int ct = 0; ct < NT; ++ct) {
            bf16x8 bf = *reinterpret_cast<const bf16x8*>(&wl[((kc * NT + ct) * 64 + lane) * 8]);
            acc[ct] = __builtin_amdgcn_mfma_f32_16x16x32_bf16(af[kc], bf, acc[ct], 0, 0, 0);
        }
    }
    #pragma unroll
    for (int ct = 0; ct < NT; ++ct) {
        #pragma unroll
        for (int r = 0; r < 4; ++r) {
            int row = row0 + kg * 4 + r;
            int col = ct * 16 + er;
            float v = acc[ct][r] + (bias ? bias[col] : 0.f);
            if (ACT) v = tanhf(v);
            out[(size_t)row * (NT * 16) + col] = f2b(v);
        }
    }
}

// ---------- GCN fused agg+combine (CSR, bf16 in/out, no atomics) ----------
__global__ __launch_bounds__(256) void k_gcn_fused(const int* __restrict__ rowptr,
                                                   const int* __restrict__ csr_src,
                                                   const short* __restrict__ hW,
                                                   const float* __restrict__ dis,
                                                   const float* __restrict__ bias,
                                                   short* __restrict__ out) {
    int wv = threadIdx.x >> 6, lane = threadIdx.x & 63;
    for (int n = blockIdx.x * 4 + wv; n < N_NODES; n += gridDim.x * 4) {
        int beg = rowptr[n], end = rowptr[n + 1];
        float a0 = 0.f, a1 = 0.f;
        for (int e = beg; e < end; ++e) {
            int s = csr_src[e];
            float ds = dis[s];
            unsigned w = *reinterpret_cast<const unsigned*>(&hW[(size_t)s * H + lane * 2]);
            a0 = fmaf(b2f((short)(w & 0xFFFF)), ds, a0);
            a1 = fmaf(b2f((short)(w >> 16)), ds, a1);
        }
        float dn = dis[n], dn2 = dn * dn;
        unsigned wn = *reinterpret_cast<const unsigned*>(&hW[(size_t)n * H + lane * 2]);
        float r0 = tanhf(dn * a0 + b2f((short)(wn & 0xFFFF)) * dn2 + bias[lane * 2]);
        float r1 = tanhf(dn * a1 + b2f((short)(wn >> 16)) * dn2 + bias[lane * 2 + 1]);
        unsigned o = (unsigned)(unsigned short)f2b(r0) | ((unsigned)(unsigned short)f2b(r1) << 16);
        *reinterpret_cast<unsigned*>(&out[(size_t)n * H + lane * 2]) = o;
    }
}

// ---------- EdgeConv via MFMA (CSR, bf16 U/V, We2 frags in LDS, register max) ----------
__global__ __launch_bounds__(256) void k_edge_mfma(const int* __restrict__ rowptr,
                                                   const int* __restrict__ csr_src,
                                                   const short* __restrict__ U,
                                                   const short* __restrict__ V,
                                                   const short* __restrict__ We2f,
                                                   const float* __restrict__ be2,
                                                   short* __restrict__ out) {
    __shared__ short wl[16384];     // 32 KB bf16 B-fragments
    for (int i = threadIdx.x * 8; i < 16384; i += 2048)
        *reinterpret_cast<f32x4*>(&wl[i]) = *reinterpret_cast<const f32x4*>(&We2f[i]);
    __syncthreads();
    int wv = threadIdx.x >> 6, lane = threadIdx.x & 63;
    int er = lane & 15;
    int kg = lane >> 4;
    int kseg = kg * 8;
    const f32x4 vzero = {0.f, 0.f, 0.f, 0.f};
    const f32x4 vninf = {-INFINITY, -INFINITY, -INFINITY, -INFINITY};
    for (int n = blockIdx.x * 4 + wv; n < N_NODES; n += gridDim.x * 4) {
        int beg = rowptr[n], end = rowptr[n + 1];
        int deg = end - beg;
        float cm[8] = {0, 0, 0, 0, 0, 0, 0, 0};
        if (deg > 0) {
            bf16x8 ub[4];
            #pragma unroll
            for (int kc = 0; kc < 4; ++kc)
                ub[kc] = *reinterpret_cast<const bf16x8*>(&U[(size_t)n * H + kc * 32 + kseg]);
            f32x4 m[8];
            #pragma unroll
            for (int ct = 0; ct < 8; ++ct) m[ct] = vninf;
            int ntiles = (deg + 15) >> 4;
            for (int t = 0; t < ntiles; ++t) {
                int ei = beg + t * 16 + er;
                int s = csr_src[ei < end ? ei : end - 1];
                bf16x8 af[4];
                #pragma unroll
                for (int kc = 0; kc < 4; ++kc) {
                    bf16x8 vb = *reinterpret_cast<const bf16x8*>(&V[(size_t)s * H + kc * 32 + kseg]);
                    #pragma unroll
                    for (int j = 0; j < 8; ++j)
                        af[kc][j] = f2b(fmaxf(b2f(ub[kc][j]) + b2f(vb[j]), 0.f));
                }
                f32x4 acc[8];
                #pragma unroll
                for (int ct = 0; ct < 8; ++ct) acc[ct] = vzero;
                #pragma unroll
                for (int kc = 0; kc < 4; ++kc) {
                    #pragma unroll
                    for (int ct = 0; ct < 8; ++ct) {
                        bf16x8 bf = *reinterpret_cast<const bf16x8*>(&wl[((kc * 8 + ct) * 64 + lane) * 8]);
                        acc[ct] = __builtin_amdgcn_mfma_f32_16x16x32_bf16(af[kc], bf, acc[ct], 0, 0, 0);
                    }
                }
                int rowbase = t * 16 + kg * 4;
                #pragma unroll
                for (int r = 0; r < 4; ++r) {
                    if (rowbase + r < deg) {
                        #pragma unroll
                        for (int ct = 0; ct < 8; ++ct)
                            m[ct][r] = fmaxf(m[ct][r], acc[ct][r]);
                    }
                }
            }
            #pragma unroll
            for (int ct = 0; ct < 8; ++ct) {
                float v = fmaxf(fmaxf(m[ct][0], m[ct][1]), fmaxf(m[ct][2], m[ct][3]));
                v = fmaxf(v, __shfl_xor(v, 16));
                v = fmaxf(v, __shfl_xor(v, 32));
                cm[ct] = v;
            }
        }
        #pragma unroll
        for (int q = 0; q < 2; ++q) {
            int ct = kg * 2 + q;
            int col = ct * 16 + er;
            float val = (deg > 0) ? (cm[ct] + be2[col]) : 0.f;
            out[(size_t)n * H + col] = f2b(tanhf(val));
        }
    }
}

// ---------- final per-node scalar + batch-mean pooling (bf16 f2) ----------
__global__ __launch_bounds__(256) void k_pool(const short* __restrict__ f2,
                                              const float* __restrict__ Wf3,
                                              const float* __restrict__ bf3,
                                              const int* __restrict__ batch,
                                              float* pooled, float* counts) {
    __shared__ float lp[G_GRAPHS];
    __shared__ float lc[G_GRAPHS];
    int tid = threadIdx.x;
    if (tid < G_GRAPHS) { lp[tid] = 0.f; lc[tid] = 0.f; }
    __syncthreads();
    int n = blockIdx.x * 256 + tid;
    if (n < N_NODES) {
        float s = bf3[0];
        #pragma unroll
        for (int k = 0; k < 32; ++k) s = fmaf(b2f(f2[(size_t)n * 32 + k]), Wf3[k], s);
        int b = batch[n];
        atomicAdd(&lp[b], s);
        atomicAdd(&lc[b], 1.0f);
    }
    __syncthreads();
    if (tid < G_GRAPHS && lc[tid] > 0.f) {
        atomicAdd(&pooled[tid], lp[tid]);
        atomicAdd(&counts[tid], lc[tid]);
    }
}

__global__ __launch_bounds__(64) void k_final(const float* pooled, const float* counts,
                                              void* out, const int* __restrict__ flag) {
    int g = threadIdx.x;
    if (g < G_GRAPHS) {
        float v = pooled[g] / fmaxf(counts[g], 1.0f);
        float s = 1.0f / (1.0f + expf(-v));
        if (*flag) ((__hip_bfloat16*)out)[g] = __float2bfloat16(s);
        else       ((float*)out)[g] = s;
    }
}

extern "C" void kernel_launch(void* const* d_in, const int* in_sizes, int n_in,
                              void* d_out, int out_size, void* d_ws, size_t ws_size,
                              hipStream_t stream) {
    const int* ei    = (const int*)d_in[1];
    const int* src   = ei;
    const int* dst   = ei + N_EDGES;
    const int* batch = (const int*)d_in[2];

    float* ws = (float*)d_ws;
    size_t off = 0;
    auto alloc = [&](size_t n) { float* p = ws + off; off += n; return p; };

    const size_t NH = (size_t)N_NODES * H;
    short* hb     = (short*)alloc(NH / 2);    // h (bf16)
    short* Ub     = (short*)alloc(NH / 2);    // U / hW / f1
    short* Vb     = (short*)alloc(NH / 2);    // V / f2
    float* xf     = alloc((size_t)N_NODES * F_IN);
    float* dis    = alloc(N_NODES);
    float* pooled = alloc(G_GRAPHS);
    float* counts = alloc(G_GRAPHS);
    int*   flag   = (int*)alloc(1);
    int*   rowptr = (int*)alloc(N_NODES + 1);
    int*   cursor = (int*)alloc(N_NODES);
    int*   csrsrc = (int*)alloc(N_EDGES);
    int*   bsums  = (int*)alloc(32);

    float* W1  = alloc(F_IN * H);
    float* b1  = alloc(H);
    float* W2  = alloc(HH);
    float* b2  = alloc(H);
    float* We1 = alloc(2 * HH);
    float* be1 = alloc(H);
    float* We2 = alloc(HH);
    float* be2 = alloc(H);
    float* Wf1 = alloc(HH);
    float* bf1 = alloc(H);
    float* Wf2 = alloc(H * 32);
    float* bf2 = alloc(32);
    float* Wf3 = alloc(32);
    float* bf3 = alloc(1);
    short* WfU  = (short*)alloc(8192);   // 16384 bf16 frag elems
    short* WfV  = (short*)alloc(8192);
    short* WfW2 = (short*)alloc(8192);
    short* WfF1 = (short*)alloc(8192);
    short* WfF2 = (short*)alloc(2048);   // NT=2
    short* We2f = (short*)alloc(8192);

    const int eB    = (N_EDGES + 255) / 256;
    const int nB    = (N_NODES + 255) / 256;
    const int scanB = (N_NODES + 2047) / 2048;
    const int mfmaB = (N_NODES / 16 + 3) / 4;      // 782 (50000 = 3125*16)
    const int gcnB  = (N_NODES + 3) / 4;           // 12500

    k_detect<<<1, 256, 0, stream>>>((const unsigned*)d_in[0], flag);
    auto cvt = [&](int idx, float* dstp, int n) {
        k_cvt<<<(n + 255) / 256, 256, 0, stream>>>(d_in[idx], dstp, n, flag);
    };
    cvt(0,  xf,  N_NODES * F_IN);
    cvt(3,  W1,  F_IN * H);
    cvt(4,  b1,  H);
    cvt(5,  W2,  HH);
    cvt(6,  b2,  H);
    cvt(7,  We1, 2 * HH);
    cvt(8,  be1, H);
    cvt(9,  We2, HH);
    cvt(10, be2, H);
    cvt(11, Wf1, HH);
    cvt(12, bf1, H);
    cvt(13, Wf2, H * 32);
    cvt(14, bf2, 32);
    cvt(15, Wf3, 32);
    cvt(16, bf3, 1);
    k_sub<<<(HH + 255) / 256, 256, 0, stream>>>(We1);
    k_prep<<<8, 256, 0, stream>>>(We1, WfU, 8);
    k_prep<<<8, 256, 0, stream>>>(We1 + HH, WfV, 8);
    k_prep<<<8, 256, 0, stream>>>(W2, WfW2, 8);
    k_prep<<<8, 256, 0, stream>>>(Wf1, WfF1, 8);
    k_prep<<<2, 256, 0, stream>>>(Wf2, WfF2, 2);
    k_prep<<<8, 256, 0, stream>>>(We2, We2f, 8);

    // CSR build (sorted by dst)
    k_zero<<<nB, 256, 0, stream>>>((float*)cursor, N_NODES);
    k_hist<<<eB, 256, 0, stream>>>(dst, cursor);
    k_scan1<<<scanB, 256, 0, stream>>>(cursor, rowptr, bsums);
    k_scan2<<<1, 1, 0, stream>>>(bsums, scanB, rowptr);
    k_scan3<<<nB, 256, 0, stream>>>(rowptr, bsums);
    k_zero<<<nB, 256, 0, stream>>>((float*)cursor, N_NODES);
    k_scatter<<<eB, 256, 0, stream>>>(src, dst, rowptr, cursor, csrsrc);
    k_dis<<<nB, 256, 0, stream>>>(rowptr, dis);
    k_zero<<<1, 256, 0, stream>>>(pooled, 2 * G_GRAPHS);

    // GCN1: hW1 = x @ W1 (f32 in, bf16 out) -> Ub ; fused agg+combine -> hb
    k_gemm_f32bf<<<(N_NODES + 7) / 8, 256, 0, stream>>>(xf, W1, Ub, N_NODES, F_IN, H);
    k_gcn_fused<<<gcnB, 256, 0, stream>>>(rowptr, csrsrc, Ub, dis, b1, hb);

    for (int iter = 0; iter < 3; ++iter) {
        k_gemm_mfma<8, 0><<<mfmaB, 256, 0, stream>>>(hb, WfU, be1, Ub, N_NODES);
        k_gemm_mfma<8, 0><<<mfmaB, 256, 0, stream>>>(hb, WfV, nullptr, Vb, N_NODES);
        k_edge_mfma<<<2048, 256, 0, stream>>>(rowptr, csrsrc, Ub, Vb, We2f, be2, hb);
        if (iter < 2) {
            k_gemm_mfma<8, 0><<<mfmaB, 256, 0, stream>>>(hb, WfW2, nullptr, Ub, N_NODES);
            k_gcn_fused<<<gcnB, 256, 0, stream>>>(rowptr, csrsrc, Ub, dis, b2, hb);
        }
    }

    // final MLP
    k_gemm_mfma<8, 1><<<mfmaB, 256, 0, stream>>>(hb, WfF1, bf1, Ub, N_NODES);
    k_gemm_mfma<2, 1><<<mfmaB, 256, 0, stream>>>(Ub, WfF2, bf2, Vb, N_NODES);
    k_pool<<<nB, 256, 0, stream>>>(Vb, Wf3, bf3, batch, pooled, counts);
    k_final<<<1, 64, 0, stream>>>(pooled, counts, d_out, flag);
}

// Round 7
// 812.208 us; speedup vs baseline: 17.3567x; 1.3098x over previous
//
#include <hip/hip_runtime.h>
#include <hip/hip_bf16.h>

#define N_NODES 50000
#define N_EDGES 800000
#define F_IN 9
#define H 128
#define G_GRAPHS 64
#define HH (H * H)

typedef short bf16x8 __attribute__((ext_vector_type(8)));
typedef float f32x4 __attribute__((ext_vector_type(4)));

static __device__ inline short f2b(float f) {
    __hip_bfloat16 h = __float2bfloat16(f);
    return *reinterpret_cast<short*>(&h);
}
static __device__ inline float blo(unsigned u) { return __uint_as_float(u << 16); }
static __device__ inline float bhi(unsigned u) { return __uint_as_float(u & 0xFFFF0000u); }

// ---------- dtype detection ----------
__global__ __launch_bounds__(256) void k_detect(const unsigned* __restrict__ x, int* flag) {
    __shared__ int cnt;
    if (threadIdx.x == 0) cnt = 0;
    __syncthreads();
    unsigned u = x[threadIdx.x];
    int e = (u >> 7) & 0xFF;
    if (e >= 0x70 && e <= 0x83) atomicAdd(&cnt, 1);
    __syncthreads();
    if (threadIdx.x == 0) *flag = (cnt >= 128) ? 1 : 0;
}

// ---------- batched convert of all float inputs ----------
struct CvtArgs { const void* src[15]; float* dst[15]; };

__global__ __launch_bounds__(256) void k_cvt_all(CvtArgs a, const int* __restrict__ flag) {
    const int sz[15] = {450000, 1152, 128, 16384, 128, 32768, 128, 16384, 128,
                        16384, 128, 4096, 32, 32, 1};
    int i = blockIdx.x * 256 + threadIdx.x;
    int fl = *flag;
    int base = 0;
    #pragma unroll
    for (int s = 0; s < 15; ++s) {
        if (i >= base && i < base + sz[s]) {
            int off = i - base;
            float v = fl ? __bfloat162float(((const __hip_bfloat16*)a.src[s])[off])
                         : ((const float*)a.src[s])[off];
            a.dst[s][off] = v;
        }
        base += sz[s];
    }
}

__global__ __launch_bounds__(256) void k_zero(float* p, int n) {
    int i = blockIdx.x * 256 + threadIdx.x;
    if (i < n) p[i] = 0.f;
}

__global__ __launch_bounds__(256) void k_sub(float* w) {
    int i = blockIdx.x * 256 + threadIdx.x;
    if (i < HH) w[i] -= w[HH + i];
}

// ---------- W[128,NT*16] f32 -> bf16 MFMA B-fragment table ----------
__global__ __launch_bounds__(256) void k_prep(const float* __restrict__ W,
                                              short* __restrict__ Wf, int NT) {
    int tid = blockIdx.x * 256 + threadIdx.x;
    int total = 4 * NT * 64;
    if (tid >= total) return;
    int kc = tid / (NT * 64);
    int ct = (tid / 64) % NT;
    int lane = tid & 63;
    int Nc = NT * 16;
    int kb = kc * 32 + (lane >> 4) * 8;
    int col = ct * 16 + (lane & 15);
    #pragma unroll
    for (int j = 0; j < 8; ++j)
        Wf[tid * 8 + j] = f2b(W[(kb + j) * Nc + col]);
}

// ---------- CSR build ----------
__global__ __launch_bounds__(256) void k_hist(const int* __restrict__ dst, int* cnt) {
    int e = blockIdx.x * 256 + threadIdx.x;
    if (e < N_EDGES) atomicAdd(&cnt[dst[e]], 1);
}

__global__ __launch_bounds__(256) void k_scan1(const int* __restrict__ deg, int* __restrict__ out,
                                               int* __restrict__ blockSums) {
    __shared__ int lds[256];
    int base = blockIdx.x * 2048;
    int t = threadIdx.x;
    int local[8];
    int s = 0;
    #pragma unroll
    for (int j = 0; j < 8; ++j) {
        int idx = base + t * 8 + j;
        int v = (idx < N_NODES) ? deg[idx] : 0;
        local[j] = s;
        s += v;
    }
    lds[t] = s;
    __syncthreads();
    if (t == 0) {
        int run = 0;
        for (int i = 0; i < 256; ++i) { int v = lds[i]; lds[i] = run; run += v; }
        blockSums[blockIdx.x] = run;
    }
    __syncthreads();
    int offs = lds[t];
    #pragma unroll
    for (int j = 0; j < 8; ++j) {
        int idx = base + t * 8 + j;
        if (idx < N_NODES) out[idx] = offs + local[j];
    }
}

__global__ void k_scan2(int* blockSums, int nb, int* rowptr) {
    int run = 0;
    for (int i = 0; i < nb; ++i) { int v = blockSums[i]; blockSums[i] = run; run += v; }
    rowptr[N_NODES] = N_EDGES;
}

__global__ __launch_bounds__(256) void k_scan3(int* rowptr, const int* __restrict__ blockSums) {
    int idx = blockIdx.x * 256 + threadIdx.x;
    if (idx < N_NODES) rowptr[idx] += blockSums[idx >> 11];
}

__global__ __launch_bounds__(256) void k_scatter(const int* __restrict__ src, const int* __restrict__ dst,
                                                 const int* __restrict__ rowptr, int* cursor,
                                                 int* __restrict__ csr_src) {
    int e = blockIdx.x * 256 + threadIdx.x;
    if (e >= N_EDGES) return;
    int d = dst[e];
    int pos = rowptr[d] + atomicAdd(&cursor[d], 1);
    csr_src[pos] = src[e];
}

__global__ __launch_bounds__(256) void k_dis(const int* __restrict__ rowptr, float* dis) {
    int n = blockIdx.x * 256 + threadIdx.x;
    if (n < N_NODES) {
        float deg = (float)(rowptr[n + 1] - rowptr[n]);
        dis[n] = rsqrtf(deg + 1.0f);
    }
}

// ---------- counts per graph (depends only on batch) ----------
__global__ __launch_bounds__(256) void k_counts(const int* __restrict__ batch, float* counts) {
    __shared__ float lc[G_GRAPHS];
    int tid = threadIdx.x;
    if (tid < G_GRAPHS) lc[tid] = 0.f;
    __syncthreads();
    int n = blockIdx.x * 256 + tid;
    if (n < N_NODES) atomicAdd(&lc[batch[n]], 1.0f);
    __syncthreads();
    if (tid < G_GRAPHS && lc[tid] > 0.f) atomicAdd(&counts[tid], lc[tid]);
}

// ---------- GCN1 GEMM: out = (x[M,9] @ W1[9,128]) * dis[row], bf16 ----------
__global__ __launch_bounds__(256) void k_gemm_f32bf_scale(const float* __restrict__ A,
                                                          const float* __restrict__ W,
                                                          const float* __restrict__ dis,
                                                          short* __restrict__ out, int M) {
    __shared__ float w_lds[F_IN * H];
    for (int i = threadIdx.x; i < F_IN * H; i += 256) w_lds[i] = W[i];
    __syncthreads();
    int row = blockIdx.x * 8 + threadIdx.x / 32;
    int c4 = (threadIdx.x & 31) << 2;
    if (row >= M) return;
    const float* a = A + (size_t)row * F_IN;
    float acc0 = 0.f, acc1 = 0.f, acc2 = 0.f, acc3 = 0.f;
    #pragma unroll
    for (int k = 0; k < F_IN; ++k) {
        float av = a[k];
        float4 w = *reinterpret_cast<const float4*>(&w_lds[k * H + c4]);
        acc0 = fmaf(av, w.x, acc0);
        acc1 = fmaf(av, w.y, acc1);
        acc2 = fmaf(av, w.z, acc2);
        acc3 = fmaf(av, w.w, acc3);
    }
    float dv = dis[row];
    short* op = &out[(size_t)row * H + c4];
    op[0] = f2b(acc0 * dv); op[1] = f2b(acc1 * dv);
    op[2] = f2b(acc2 * dv); op[3] = f2b(acc3 * dv);
}

// ---------- dual MFMA GEMM: U = A@WU + be1 ; V = A@WV (A-frags loaded once) ----------
__global__ __launch_bounds__(256) void k_gemm_dual(const short* __restrict__ A,
                                                   const short* __restrict__ WfU,
                                                   const short* __restrict__ WfV,
                                                   const float* __restrict__ be1,
                                                   short* __restrict__ U,
                                                   short* __restrict__ V, int M) {
    __shared__ short wl[32768];
    for (int i = threadIdx.x * 8; i < 16384; i += 2048) {
        *reinterpret_cast<f32x4*>(&wl[i])         = *reinterpret_cast<const f32x4*>(&WfU[i]);
        *reinterpret_cast<f32x4*>(&wl[16384 + i]) = *reinterpret_cast<const f32x4*>(&WfV[i]);
    }
    __syncthreads();
    int wv = threadIdx.x >> 6, lane = threadIdx.x & 63;
    int er = lane & 15, kg = lane >> 4;
    int row0 = (blockIdx.x * 4 + wv) * 16;
    if (row0 >= M) return;
    bf16x8 af[4];
    #pragma unroll
    for (int kc = 0; kc < 4; ++kc)
        af[kc] = *reinterpret_cast<const bf16x8*>(&A[(size_t)(row0 + er) * H + kc * 32 + kg * 8]);
    const f32x4 vzero = {0.f, 0.f, 0.f, 0.f};
    f32x4 acc[8];
    // U pass
    #pragma unroll
    for (int ct = 0; ct < 8; ++ct) acc[ct] = vzero;
    #pragma unroll
    for (int kc = 0; kc < 4; ++kc)
        #pragma unroll
        for (int ct = 0; ct < 8; ++ct) {
            bf16x8 bf = *reinterpret_cast<const bf16x8*>(&wl[((kc * 8 + ct) * 64 + lane) * 8]);
            acc[ct] = __builtin_amdgcn_mfma_f32_16x16x32_bf16(af[kc], bf, acc[ct], 0, 0, 0);
        }
    #pragma unroll
    for (int ct = 0; ct < 8; ++ct) {
        int col = ct * 16 + er;
        float bv = be1[col];
        #pragma unroll
        for (int r = 0; r < 4; ++r)
            U[(size_t)(row0 + kg * 4 + r) * H + col] = f2b(acc[ct][r] + bv);
    }
    // V pass
    #pragma unroll
    for (int ct = 0; ct < 8; ++ct) acc[ct] = vzero;
    #pragma unroll
    for (int kc = 0; kc < 4; ++kc)
        #pragma unroll
        for (int ct = 0; ct < 8; ++ct) {
            bf16x8 bf = *reinterpret_cast<const bf16x8*>(&wl[16384 + ((kc * 8 + ct) * 64 + lane) * 8]);
            acc[ct] = __builtin_amdgcn_mfma_f32_16x16x32_bf16(af[kc], bf, acc[ct], 0, 0, 0);
        }
    #pragma unroll
    for (int ct = 0; ct < 8; ++ct) {
        int col = ct * 16 + er;
        #pragma unroll
        for (int r = 0; r < 4; ++r)
            V[(size_t)(row0 + kg * 4 + r) * H + col] = f2b(acc[ct][r]);
    }
}

// ---------- MFMA GEMM with dis-scale epilogue: out = (A@W) * dis[row] ----------
__global__ __launch_bounds__(256) void k_gemm_scale(const short* __restrict__ A,
                                                    const short* __restrict__ Wf,
                                                    const float* __restrict__ dis,
                                                    short* __restrict__ out, int M) {
    __shared__ short wl[16384];
    for (int i = threadIdx.x * 8; i < 16384; i += 2048)
        *reinterpret_cast<f32x4*>(&wl[i]) = *reinterpret_cast<const f32x4*>(&Wf[i]);
    __syncthreads();
    int wv = threadIdx.x >> 6, lane = threadIdx.x & 63;
    int er = lane & 15, kg = lane >> 4;
    int row0 = (blockIdx.x * 4 + wv) * 16;
    if (row0 >= M) return;
    bf16x8 af[4];
    #pragma unroll
    for (int kc = 0; kc < 4; ++kc)
        af[kc] = *reinterpret_cast<const bf16x8*>(&A[(size_t)(row0 + er) * H + kc * 32 + kg * 8]);
    const f32x4 vzero = {0.f, 0.f, 0.f, 0.f};
    f32x4 acc[8];
    #pragma unroll
    for (int ct = 0; ct < 8; ++ct) acc[ct] = vzero;
    #pragma unroll
    for (int kc = 0; kc < 4; ++kc)
        #pragma unroll
        for (int ct = 0; ct < 8; ++ct) {
            bf16x8 bf = *reinterpret_cast<const bf16x8*>(&wl[((kc * 8 + ct) * 64 + lane) * 8]);
            acc[ct] = __builtin_amdgcn_mfma_f32_16x16x32_bf16(af[kc], bf, acc[ct], 0, 0, 0);
        }
    float dv[4];
    #pragma unroll
    for (int r = 0; r < 4; ++r) dv[r] = dis[row0 + kg * 4 + r];
    #pragma unroll
    for (int ct = 0; ct < 8; ++ct) {
        int col = ct * 16 + er;
        #pragma unroll
        for (int r = 0; r < 4; ++r)
            out[(size_t)(row0 + kg * 4 + r) * H + col] = f2b(acc[ct][r] * dv[r]);
    }
}

// ---------- GCN fused agg+combine (CSR, pre-scaled rows, 4-way unrolled) ----------
// out = tanh(dn*(sum_e scaled[s] + scaled[n]) + bias)
__global__ __launch_bounds__(256) void k_gcn_fused(const int* __restrict__ rowptr,
                                                   const int* __restrict__ csr_src,
                                                   const short* __restrict__ hWs,
                                                   const float* __restrict__ dis,
                                                   const float* __restrict__ bias,
                                                   short* __restrict__ out) {
    int wv = threadIdx.x >> 6, lane = threadIdx.x & 63;
    const unsigned* hw = (const unsigned*)hWs;
    for (int n = blockIdx.x * 4 + wv; n < N_NODES; n += gridDim.x * 4) {
        int beg = rowptr[n], end = rowptr[n + 1];
        float a0 = 0.f, a1 = 0.f, b0 = 0.f, b1 = 0.f;
        float c0 = 0.f, c1 = 0.f, d0 = 0.f, d1 = 0.f;
        int e = beg;
        for (; e + 4 <= end; e += 4) {
            int s0 = csr_src[e], s1 = csr_src[e + 1], s2 = csr_src[e + 2], s3 = csr_src[e + 3];
            unsigned w0 = hw[(size_t)s0 * 64 + lane];
            unsigned w1 = hw[(size_t)s1 * 64 + lane];
            unsigned w2 = hw[(size_t)s2 * 64 + lane];
            unsigned w3 = hw[(size_t)s3 * 64 + lane];
            a0 += blo(w0); a1 += bhi(w0);
            b0 += blo(w1); b1 += bhi(w1);
            c0 += blo(w2); c1 += bhi(w2);
            d0 += blo(w3); d1 += bhi(w3);
        }
        for (; e < end; ++e) {
            unsigned w = hw[(size_t)csr_src[e] * 64 + lane];
            a0 += blo(w); a1 += bhi(w);
        }
        float s0f = (a0 + b0) + (c0 + d0);
        float s1f = (a1 + b1) + (c1 + d1);
        float dn = dis[n];
        unsigned wn = hw[(size_t)n * 64 + lane];
        float r0 = tanhf(dn * (s0f + blo(wn)) + bias[lane * 2]);
        float r1 = tanhf(dn * (s1f + bhi(wn)) + bias[lane * 2 + 1]);
        unsigned o = (unsigned)(unsigned short)f2b(r0) | ((unsigned)(unsigned short)f2b(r1) << 16);
        *reinterpret_cast<unsigned*>(&out[(size_t)n * H + lane * 2]) = o;
    }
}

// ---------- EdgeConv via MFMA (no mask: padded rows duplicate last edge; V prefetch) ----------
__global__ __launch_bounds__(256) void k_edge_mfma(const int* __restrict__ rowptr,
                                                   const int* __restrict__ csr_src,
                                                   const short* __restrict__ U,
                                                   const short* __restrict__ V,
                                                   const short* __restrict__ We2f,
                                                   const float* __restrict__ be2,
                                                   short* __restrict__ out) {
    __shared__ short wl[16384];
    for (int i = threadIdx.x * 8; i < 16384; i += 2048)
        *reinterpret_cast<f32x4*>(&wl[i]) = *reinterpret_cast<const f32x4*>(&We2f[i]);
    __syncthreads();
    int wv = threadIdx.x >> 6, lane = threadIdx.x & 63;
    int er = lane & 15, kg = lane >> 4, kseg = kg * 8;
    const f32x4 vzero = {0.f, 0.f, 0.f, 0.f};
    for (int n = blockIdx.x * 4 + wv; n < N_NODES; n += gridDim.x * 4) {
        int beg = rowptr[n], end = rowptr[n + 1];
        int deg = end - beg;
        if (deg > 0) {
            uint4 ub[4];
            #pragma unroll
            for (int kc = 0; kc < 4; ++kc)
                ub[kc] = *reinterpret_cast<const uint4*>(&U[(size_t)n * H + kc * 32 + kseg]);
            float cm[8];
            #pragma unroll
            for (int ct = 0; ct < 8; ++ct) cm[ct] = -INFINITY;
            int ntiles = (deg + 15) >> 4;
            int ei0 = beg + er;
            int sCur = csr_src[ei0 < end ? ei0 : end - 1];
            uint4 vb[4];
            #pragma unroll
            for (int kc = 0; kc < 4; ++kc)
                vb[kc] = *reinterpret_cast<const uint4*>(&V[(size_t)sCur * H + kc * 32 + kseg]);
            for (int t = 0; t < ntiles; ++t) {
                uint4 vn[4];
                int more = (t + 1 < ntiles);
                if (more) {
                    int ei = beg + (t + 1) * 16 + er;
                    int sNext = csr_src[ei < end ? ei : end - 1];
                    #pragma unroll
                    for (int kc = 0; kc < 4; ++kc)
                        vn[kc] = *reinterpret_cast<const uint4*>(&V[(size_t)sNext * H + kc * 32 + kseg]);
                }
                // A-fragments: relu(U + V) -> bf16
                bf16x8 af[4];
                #pragma unroll
                for (int kc = 0; kc < 4; ++kc) {
                    unsigned uu, vv;
                    uu = ub[kc].x; vv = vb[kc].x;
                    af[kc][0] = f2b(fmaxf(blo(uu) + blo(vv), 0.f));
                    af[kc][1] = f2b(fmaxf(bhi(uu) + bhi(vv), 0.f));
                    uu = ub[kc].y; vv = vb[kc].y;
                    af[kc][2] = f2b(fmaxf(blo(uu) + blo(vv), 0.f));
                    af[kc][3] = f2b(fmaxf(bhi(uu) + bhi(vv), 0.f));
                    uu = ub[kc].z; vv = vb[kc].z;
                    af[kc][4] = f2b(fmaxf(blo(uu) + blo(vv), 0.f));
                    af[kc][5] = f2b(fmaxf(bhi(uu) + bhi(vv), 0.f));
                    uu = ub[kc].w; vv = vb[kc].w;
                    af[kc][6] = f2b(fmaxf(blo(uu) + blo(vv), 0.f));
                    af[kc][7] = f2b(fmaxf(bhi(uu) + bhi(vv), 0.f));
                }
                f32x4 acc[8];
                #pragma unroll
                for (int ct = 0; ct < 8; ++ct) acc[ct] = vzero;
                #pragma unroll
                for (int kc = 0; kc < 4; ++kc)
                    #pragma unroll
                    for (int ct = 0; ct < 8; ++ct) {
                        bf16x8 bf = *reinterpret_cast<const bf16x8*>(&wl[((kc * 8 + ct) * 64 + lane) * 8]);
                        acc[ct] = __builtin_amdgcn_mfma_f32_16x16x32_bf16(af[kc], bf, acc[ct], 0, 0, 0);
                    }
                #pragma unroll
                for (int ct = 0; ct < 8; ++ct)
                    cm[ct] = fmaxf(cm[ct], fmaxf(fmaxf(acc[ct][0], acc[ct][1]),
                                                 fmaxf(acc[ct][2], acc[ct][3])));
                if (more) {
                    #pragma unroll
                    for (int kc = 0; kc < 4; ++kc) vb[kc] = vn[kc];
                    int ei = beg + (t + 1) * 16 + er;
                    sCur = csr_src[ei < end ? ei : end - 1];
                }
            }
            #pragma unroll
            for (int ct = 0; ct < 8; ++ct) {
                float v = cm[ct];
                v = fmaxf(v, __shfl_xor(v, 16));
                v = fmaxf(v, __shfl_xor(v, 32));
                cm[ct] = v;
            }
            float vA, vB;
            if (kg == 0)      { vA = cm[0]; vB = cm[1]; }
            else if (kg == 1) { vA = cm[2]; vB = cm[3]; }
            else if (kg == 2) { vA = cm[4]; vB = cm[5]; }
            else              { vA = cm[6]; vB = cm[7]; }
            int colA = (kg * 2) * 16 + er;
            int colB = (kg * 2 + 1) * 16 + er;
            out[(size_t)n * H + colA] = f2b(tanhf(vA + be2[colA]));
            out[(size_t)n * H + colB] = f2b(tanhf(vB + be2[colB]));
        } else {
            int colA = (kg * 2) * 16 + er;
            int colB = (kg * 2 + 1) * 16 + er;
            out[(size_t)n * H + colA] = 0;
            out[(size_t)n * H + colB] = 0;
        }
    }
}

// ---------- fused final MLP + pooling ----------
__global__ __launch_bounds__(256) void k_final_mlp(const short* __restrict__ h,
                                                   const short* __restrict__ WfF1,
                                                   const short* __restrict__ WfF2,
                                                   const float* __restrict__ bf1,
                                                   const float* __restrict__ bf2,
                                                   const float* __restrict__ Wf3,
                                                   const float* __restrict__ bf3,
                                                   const int* __restrict__ batch,
                                                   float* pooled, int M) {
    __shared__ short wl1[16384];
    __shared__ short wl2[4096];
    __shared__ short tb[4][2048];
    __shared__ float lp[G_GRAPHS];
    for (int i = threadIdx.x * 8; i < 16384; i += 2048)
        *reinterpret_cast<f32x4*>(&wl1[i]) = *reinterpret_cast<const f32x4*>(&WfF1[i]);
    for (int i = threadIdx.x * 8; i < 4096; i += 2048)
        *reinterpret_cast<f32x4*>(&wl2[i]) = *reinterpret_cast<const f32x4*>(&WfF2[i]);
    if (threadIdx.x < G_GRAPHS) lp[threadIdx.x] = 0.f;
    __syncthreads();
    int wv = threadIdx.x >> 6, lane = threadIdx.x & 63;
    int er = lane & 15, kg = lane >> 4;
    int row0 = (blockIdx.x * 4 + wv) * 16;
    bool active = row0 < M;
    const f32x4 vzero = {0.f, 0.f, 0.f, 0.f};
    if (active) {
        bf16x8 af[4];
        #pragma unroll
        for (int kc = 0; kc < 4; ++kc)
            af[kc] = *reinterpret_cast<const bf16x8*>(&h[(size_t)(row0 + er) * H + kc * 32 + kg * 8]);
        f32x4 acc[8];
        #pragma unroll
        for (int ct = 0; ct < 8; ++ct) acc[ct] = vzero;
        #pragma unroll
        for (int kc = 0; kc < 4; ++kc)
            #pragma unroll
            for (int ct = 0; ct < 8; ++ct) {
                bf16x8 bf = *reinterpret_cast<const bf16x8*>(&wl1[((kc * 8 + ct) * 64 + lane) * 8]);
                acc[ct] = __builtin_amdgcn_mfma_f32_16x16x32_bf16(af[kc], bf, acc[ct], 0, 0, 0);
            }
        #pragma unroll
        for (int ct = 0; ct < 8; ++ct) {
            int col = ct * 16 + er;
            float bv = bf1[col];
            #pragma unroll
            for (int r = 0; r < 4; ++r)
                tb[wv][(kg * 4 + r) * 128 + col] = f2b(tanhf(acc[ct][r] + bv));
        }
    }
    __syncthreads();
    if (active) {
        bf16x8 af2[4];
        #pragma unroll
        for (int kc = 0; kc < 4; ++kc)
            af2[kc] = *reinterpret_cast<const bf16x8*>(&tb[wv][er * 128 + kc * 32 + kg * 8]);
        f32x4 a2[2];
        a2[0] = vzero; a2[1] = vzero;
        #pragma unroll
        for (int kc = 0; kc < 4; ++kc)
            #pragma unroll
            for (int ct = 0; ct < 2; ++ct) {
                bf16x8 bf = *reinterpret_cast<const bf16x8*>(&wl2[((kc * 2 + ct) * 64 + lane) * 8]);
                a2[ct] = __builtin_amdgcn_mfma_f32_16x16x32_bf16(af2[kc], bf, a2[ct], 0, 0, 0);
            }
        float w3a = Wf3[er], w3b = Wf3[16 + er];
        float b2a = bf2[er], b2b = bf2[16 + er];
        float bf3v = bf3[0];
        float psum[4];
        #pragma unroll
        for (int r = 0; r < 4; ++r) {
            float f2a = tanhf(a2[0][r] + b2a);
            float f2c = tanhf(a2[1][r] + b2b);
            float p = f2a * w3a + f2c * w3b;
            p += __shfl_xor(p, 1);
            p += __shfl_xor(p, 2);
            p += __shfl_xor(p, 4);
            p += __shfl_xor(p, 8);
            psum[r] = p + bf3v;
        }
        if (er == 0) {
            #pragma unroll
            for (int r = 0; r < 4; ++r) {
                int n = row0 + kg * 4 + r;
                if (n < M) atomicAdd(&lp[batch[n]], psum[r]);
            }
        }
    }
    __syncthreads();
    if (threadIdx.x < G_GRAPHS && lp[threadIdx.x] != 0.f)
        atomicAdd(&pooled[threadIdx.x], lp[threadIdx.x]);
}

__global__ __launch_bounds__(64) void k_final(const float* pooled, const float* counts,
                                              void* out, const int* __restrict__ flag) {
    int g = threadIdx.x;
    if (g < G_GRAPHS) {
        float v = pooled[g] / fmaxf(counts[g], 1.0f);
        float s = 1.0f / (1.0f + expf(-v));
        if (*flag) ((__hip_bfloat16*)out)[g] = __float2bfloat16(s);
        else       ((float*)out)[g] = s;
    }
}

extern "C" void kernel_launch(void* const* d_in, const int* in_sizes, int n_in,
                              void* d_out, int out_size, void* d_ws, size_t ws_size,
                              hipStream_t stream) {
    const int* ei    = (const int*)d_in[1];
    const int* src   = ei;
    const int* dst   = ei + N_EDGES;
    const int* batch = (const int*)d_in[2];

    float* ws = (float*)d_ws;
    size_t off = 0;
    auto alloc = [&](size_t n) { off = (off + 3) & ~(size_t)3; float* p = ws + off; off += n; return p; };

    const size_t NH = (size_t)N_NODES * H;
    short* hb     = (short*)alloc(NH / 2);
    short* Ub     = (short*)alloc(NH / 2);
    short* Vb     = (short*)alloc(NH / 2);
    float* xf     = alloc((size_t)N_NODES * F_IN);
    float* dis    = alloc(N_NODES);
    float* pooled = alloc(G_GRAPHS);
    float* counts = alloc(G_GRAPHS);
    int*   flag   = (int*)alloc(1);
    int*   rowptr = (int*)alloc(N_NODES + 1);
    int*   cursor = (int*)alloc(N_NODES);
    int*   csrsrc = (int*)alloc(N_EDGES);
    int*   bsums  = (int*)alloc(32);

    float* W1  = alloc(F_IN * H);
    float* b1  = alloc(H);
    float* W2  = alloc(HH);
    float* b2  = alloc(H);
    float* We1 = alloc(2 * HH);
    float* be1 = alloc(H);
    float* We2 = alloc(HH);
    float* be2 = alloc(H);
    float* Wf1 = alloc(HH);
    float* bf1 = alloc(H);
    float* Wf2 = alloc(H * 32);
    float* bf2 = alloc(32);
    float* Wf3 = alloc(32);
    float* bf3 = alloc(4);
    short* WfU  = (short*)alloc(8192);
    short* WfV  = (short*)alloc(8192);
    short* WfW2 = (short*)alloc(8192);
    short* WfF1 = (short*)alloc(8192);
    short* WfF2 = (short*)alloc(2048);
    short* We2f = (short*)alloc(8192);

    const int eB    = (N_EDGES + 255) / 256;
    const int nB    = (N_NODES + 255) / 256;
    const int scanB = (N_NODES + 2047) / 2048;
    const int mfmaB = (N_NODES / 16 + 3) / 4;      // 782
    const int gcnB  = (N_NODES + 3) / 4;           // 12500

    k_detect<<<1, 256, 0, stream>>>((const unsigned*)d_in[0], flag);

    CvtArgs ca;
    const int srcIdx[15] = {0, 3, 4, 5, 6, 7, 8, 9, 10, 11, 12, 13, 14, 15, 16};
    float* dsts[15] = {xf, W1, b1, W2, b2, We1, be1, We2, be2, Wf1, bf1, Wf2, bf2, Wf3, bf3};
    for (int s = 0; s < 15; ++s) { ca.src[s] = d_in[srcIdx[s]]; ca.dst[s] = dsts[s]; }
    const int cvtTotal = 450000 + 1152 + 128 + 16384 + 128 + 32768 + 128 + 16384 + 128
                       + 16384 + 128 + 4096 + 32 + 32 + 1;       // 537873
    k_cvt_all<<<(cvtTotal + 255) / 256, 256, 0, stream>>>(ca, flag);   // 2102 blocks

    k_sub<<<(HH + 255) / 256, 256, 0, stream>>>(We1);
    k_prep<<<8, 256, 0, stream>>>(We1, WfU, 8);
    k_prep<<<8, 256, 0, stream>>>(We1 + HH, WfV, 8);
    k_prep<<<8, 256, 0, stream>>>(W2, WfW2, 8);
    k_prep<<<8, 256, 0, stream>>>(Wf1, WfF1, 8);
    k_prep<<<2, 256, 0, stream>>>(Wf2, WfF2, 2);
    k_prep<<<8, 256, 0, stream>>>(We2, We2f, 8);

    // CSR build (sorted by dst)
    k_zero<<<nB, 256, 0, stream>>>((float*)cursor, N_NODES);
    k_hist<<<eB, 256, 0, stream>>>(dst, cursor);
    k_scan1<<<scanB, 256, 0, stream>>>(cursor, rowptr, bsums);
    k_scan2<<<1, 1, 0, stream>>>(bsums, scanB, rowptr);
    k_scan3<<<nB, 256, 0, stream>>>(rowptr, bsums);
    k_zero<<<nB, 256, 0, stream>>>((float*)cursor, N_NODES);
    k_scatter<<<eB, 256, 0, stream>>>(src, dst, rowptr, cursor, csrsrc);
    k_dis<<<nB, 256, 0, stream>>>(rowptr, dis);
    k_zero<<<1, 256, 0, stream>>>(pooled, 2 * G_GRAPHS);
    k_counts<<<nB, 256, 0, stream>>>(batch, counts);

    // GCN1: scaled = (x@W1)*dis -> Ub ; fused agg+combine -> hb
    k_gemm_f32bf_scale<<<(N_NODES + 7) / 8, 256, 0, stream>>>(xf, W1, dis, Ub, N_NODES);
    k_gcn_fused<<<gcnB, 256, 0, stream>>>(rowptr, csrsrc, Ub, dis, b1, hb);

    for (int iter = 0; iter < 3; ++iter) {
        k_gemm_dual<<<mfmaB, 256, 0, stream>>>(hb, WfU, WfV, be1, Ub, Vb, N_NODES);
        k_edge_mfma<<<2048, 256, 0, stream>>>(rowptr, csrsrc, Ub, Vb, We2f, be2, hb);
        if (iter < 2) {
            k_gemm_scale<<<mfmaB, 256, 0, stream>>>(hb, WfW2, dis, Ub, N_NODES);
            k_gcn_fused<<<gcnB, 256, 0, stream>>>(rowptr, csrsrc, Ub, dis, b2, hb);
        }
    }

    k_final_mlp<<<mfmaB, 256, 0, stream>>>(hb, WfF1, WfF2, bf1, bf2, Wf3, bf3,
                                           batch, pooled, N_NODES);
    k_final<<<1, 64, 0, stream>>>(pooled, counts, d_out, flag);
}